// Round 1
// baseline (1670.721 us; speedup 1.0000x reference)
//
#include <hip/hip_runtime.h>

#define NF 64
#define BURST 14
#define NPIX 16384           // H*W = 128*128
#define CN (NF * NPIX)       // per-batch elements = 1,048,576

// ---------------------------------------------------------------------------
// Generic NN GEMM: Out[b] = W[b] @ X[b] (+bias), out tile 64x64 per block.
// W: rows o (stride wRS), X: rows c (stride xRS = Npix), per-batch strides.
// MODE 0: linear store out[b*oBS + o*Npix + p]
// MODE 1: part-1 unscramble store: addr = ((p>>8)<<14) + (p&255)*64 + o
// MODE 2: part-2/3 unscramble store: addr = ((p>>7)<<14) + (p&127)*128 + o
// ACC: read-modify-write accumulate. SUMB>0: loop batches inside (grid.z==1).
// grid: (Npix/64, O/64, nbatch)  block: 256
// ---------------------------------------------------------------------------
template <int MODE, bool ACC, int SUMB>
__global__ __launch_bounds__(256) void gemm_nn(
    const float* __restrict__ Wp, const float* __restrict__ Xp,
    float* __restrict__ Op, const float* __restrict__ bias,
    int Cd, int Npix, int wBS, int xBS, int oBS, int wRS, int xRS)
{
    __shared__ float Ws[64][65];  // [c_local][o_local]
    __shared__ float Xs[64][65];  // [c_local][p_local]
    const int p0 = blockIdx.x * 64;
    const int o0 = blockIdx.y * 64;
    const int b  = blockIdx.z;
    const int tid = threadIdx.x;
    const int to = tid & 15;   // o-quad index
    const int tp = tid >> 4;   // p-quad index

    float acc[4][4];
#pragma unroll
    for (int i = 0; i < 4; ++i)
#pragma unroll
        for (int j = 0; j < 4; ++j) acc[i][j] = 0.f;

    const int nb = (SUMB > 0) ? SUMB : 1;
    for (int bb = 0; bb < nb; ++bb) {
        const int bidx = (SUMB > 0) ? bb : b;
        const float* Wb = Wp + (size_t)bidx * wBS;
        const float* Xb = Xp + (size_t)bidx * xBS;
        for (int cc = 0; cc < Cd; cc += 64) {
            const int t = tid & 63, rb = tid >> 6;
#pragma unroll
            for (int r = rb; r < 64; r += 4) {
                Ws[t][r] = Wb[(size_t)(o0 + r) * wRS + cc + t];
                Xs[r][t] = Xb[(size_t)(cc + r) * xRS + p0 + t];
            }
            __syncthreads();
#pragma unroll 8
            for (int j = 0; j < 64; ++j) {
                float xv[4], wv[4];
#pragma unroll
                for (int jj = 0; jj < 4; ++jj) xv[jj] = Xs[j][tp * 4 + jj];
#pragma unroll
                for (int i = 0; i < 4; ++i) wv[i] = Ws[j][to * 4 + i];
#pragma unroll
                for (int i = 0; i < 4; ++i)
#pragma unroll
                    for (int jj = 0; jj < 4; ++jj) acc[i][jj] += wv[i] * xv[jj];
            }
            __syncthreads();
        }
    }

#pragma unroll
    for (int i = 0; i < 4; ++i) {
        const int o = o0 + to * 4 + i;
        const float bv = bias ? bias[o] : 0.f;
#pragma unroll
        for (int j = 0; j < 4; ++j) {
            const int p = p0 + tp * 4 + j;
            const float v = acc[i][j] + bv;
            size_t addr;
            if (MODE == 0) addr = (size_t)b * oBS + (size_t)o * Npix + p;
            else if (MODE == 1) addr = (size_t)b * oBS + (((size_t)(p >> 8)) << 14) + (size_t)(p & 255) * 64 + o;
            else addr = (size_t)b * oBS + (((size_t)(p >> 7)) << 14) + (size_t)(p & 127) * 128 + o;
            if (ACC) Op[addr] += v; else Op[addr] = v;
        }
    }
}

// ---------------------------------------------------------------------------
// NT GEMM with K-split + atomic accumulate: F[b, m, n] += A[b,m,:K] . B[b,n,:K]
// grid: (mtiles*ntiles, K/1024, nbatch)  block: 256
// ---------------------------------------------------------------------------
__global__ __launch_bounds__(256) void gemm_nt(
    const float* __restrict__ A, const float* __restrict__ B, float* __restrict__ F,
    int K, int aBS, int aRS, int bBS, int bRS, int fBS, int fRS, int mtiles)
{
    __shared__ float As[64][65];
    __shared__ float Bs[64][65];
    const int tileId = blockIdx.x;
    const int m0 = (tileId % mtiles) * 64;
    const int n0 = (tileId / mtiles) * 64;
    const int k0 = blockIdx.y * 1024;
    const int b = blockIdx.z;
    const float* Ab = A + (size_t)b * aBS;
    const float* Bb = B + (size_t)b * bBS;
    const int tid = threadIdx.x;
    const int tm = tid & 15, tn = tid >> 4;

    float acc[4][4];
#pragma unroll
    for (int i = 0; i < 4; ++i)
#pragma unroll
        for (int j = 0; j < 4; ++j) acc[i][j] = 0.f;

    for (int kk = k0; kk < k0 + 1024; kk += 64) {
        const int t = tid & 63, rb = tid >> 6;
#pragma unroll
        for (int r = rb; r < 64; r += 4) {
            As[r][t] = Ab[(size_t)(m0 + r) * aRS + kk + t];
            Bs[r][t] = Bb[(size_t)(n0 + r) * bRS + kk + t];
        }
        __syncthreads();
#pragma unroll 8
        for (int t2 = 0; t2 < 64; ++t2) {
            float av[4], bv[4];
#pragma unroll
            for (int i = 0; i < 4; ++i) av[i] = As[tm * 4 + i][t2];
#pragma unroll
            for (int j = 0; j < 4; ++j) bv[j] = Bs[tn * 4 + j][t2];
#pragma unroll
            for (int i = 0; i < 4; ++i)
#pragma unroll
                for (int j = 0; j < 4; ++j) acc[i][j] += av[i] * bv[j];
        }
        __syncthreads();
    }
#pragma unroll
    for (int i = 0; i < 4; ++i)
#pragma unroll
        for (int j = 0; j < 4; ++j)
            atomicAdd(&F[(size_t)b * fBS + (size_t)(m0 + tm * 4 + i) * fRS + (n0 + tn * 4 + j)], acc[i][j]);
}

// softmax over c for fixed (b,d): F[b*4096 + c*64 + d], grid BURST, block 64
__global__ void softmax_col64(float* __restrict__ F)
{
    float* Fb = F + (size_t)blockIdx.x * 4096;
    const int d = threadIdx.x;
    float r[64];
    float mx = -1e30f;
#pragma unroll
    for (int c = 0; c < 64; ++c) { r[c] = Fb[c * 64 + d]; mx = fmaxf(mx, r[c]); }
    float s = 0.f;
#pragma unroll
    for (int c = 0; c < 64; ++c) { r[c] = __expf(r[c] - mx); s += r[c]; }
    const float inv = 1.f / s;
#pragma unroll
    for (int c = 0; c < 64; ++c) Fb[c * 64 + d] = r[c] * inv;
}

// softmax over i for fixed (b,j): F[b*16384 + i*128 + j], grid BURST, block 128
__global__ void softmax_col128(float* __restrict__ F)
{
    float* Fb = F + (size_t)blockIdx.x * 16384;
    const int j = threadIdx.x;
    float mx = -1e30f;
    for (int i = 0; i < 128; ++i) mx = fmaxf(mx, Fb[i * 128 + j]);
    float s = 0.f;
    for (int i = 0; i < 128; ++i) {
        float e = __expf(Fb[i * 128 + j] - mx);
        Fb[i * 128 + j] = e; s += e;
    }
    const float inv = 1.f / s;
    for (int i = 0; i < 128; ++i) Fb[i * 128 + j] *= inv;
}

// Precompute folded fusion matrices:
//  blocks 0..41: M[g][b][o][c'] = sum_c2 fus_w[o, g*896+b*64+c2] * Wg[c2,c']
//  block  42:    W_comb[o][bc]  = sum_g fus_w[o, g*896+bc]
//                cb[o] = fus_b[o] + sum_{g,b,c2} fus_w[o, g*896+b*64+c2]*bWg[c2]
__global__ void precompute(const float* __restrict__ fus_w, const float* __restrict__ fus_b,
                           const float* __restrict__ Wc, const float* __restrict__ bWc,
                           const float* __restrict__ Wh, const float* __restrict__ bWh,
                           const float* __restrict__ Ww, const float* __restrict__ bWw,
                           float* __restrict__ M, float* __restrict__ Wcomb, float* __restrict__ cb)
{
    const int blk = blockIdx.x, tid = threadIdx.x;
    if (blk < 42) {
        const int g = blk / 14, b = blk % 14;
        const float* Wg = (g == 0) ? Wc : (g == 1) ? Wh : Ww;
        float* Mout = M + ((size_t)g * 14 + b) * 4096;
        const int o = tid >> 2;
        for (int i = 0; i < 16; ++i) {
            const int cp = (tid & 3) * 16 + i;
            float s = 0.f;
            for (int c2 = 0; c2 < 64; ++c2)
                s += fus_w[o * 2688 + g * 896 + b * 64 + c2] * Wg[c2 * 64 + cp];
            Mout[o * 64 + cp] = s;
        }
    } else {
        for (int e = tid; e < 64 * 896; e += 256) {
            const int o = e / 896, bc = e % 896;
            Wcomb[e] = fus_w[o * 2688 + bc] + fus_w[o * 2688 + 896 + bc] + fus_w[o * 2688 + 1792 + bc];
        }
        if (tid < 64) {
            float s = fus_b[tid];
            for (int ch = 0; ch < 2688; ++ch) {
                const int g = ch / 896, c2 = ch % 64;
                const float* bg = (g == 0) ? bWc : (g == 1) ? bWh : bWw;
                s += fus_w[tid * 2688 + ch] * bg[c2];
            }
            cb[tid] = s;
        }
    }
}

__global__ void leaky_kernel(float* __restrict__ o, int n)
{
    const int i = blockIdx.x * 256 + threadIdx.x;
    if (i < n) { const float v = o[i]; o[i] = v >= 0.f ? v : 0.2f * v; }
}

extern "C" void kernel_launch(void* const* d_in, const int* in_sizes, int n_in,
                              void* d_out, int out_size, void* d_ws, size_t ws_size,
                              hipStream_t stream)
{
    const float* x     = (const float*)d_in[0];
    const float* gc_w  = (const float*)d_in[1];
    const float* gc_b  = (const float*)d_in[2];
    const float* thc_w = (const float*)d_in[3];
    const float* thc_b = (const float*)d_in[4];
    const float* phc_w = (const float*)d_in[5];
    const float* phc_b = (const float*)d_in[6];
    const float* Wc_w  = (const float*)d_in[7];
    const float* Wc_b  = (const float*)d_in[8];
    const float* gh_w  = (const float*)d_in[9];
    const float* gh_b  = (const float*)d_in[10];
    const float* thh_w = (const float*)d_in[11];
    const float* thh_b = (const float*)d_in[12];
    const float* phh_w = (const float*)d_in[13];
    const float* phh_b = (const float*)d_in[14];
    const float* Wh_w  = (const float*)d_in[15];
    const float* Wh_b  = (const float*)d_in[16];
    const float* gw_w  = (const float*)d_in[17];
    const float* gw_b  = (const float*)d_in[18];
    const float* thw_w = (const float*)d_in[19];
    const float* thw_b = (const float*)d_in[20];
    const float* phw_w = (const float*)d_in[21];
    const float* phw_b = (const float*)d_in[22];
    const float* Ww_w  = (const float*)d_in[23];
    const float* Ww_b  = (const float*)d_in[24];
    const float* fus_w = (const float*)d_in[25];
    const float* fus_b = (const float*)d_in[26];

    float* out = (float*)d_out;
    float* ws = (float*)d_ws;

    float* buf1  = ws;                      // 14,680,064 (th -> g)
    float* buf2  = buf1 + (size_t)BURST * CN;  // 14,680,064 (ph)
    float* buf3  = buf2 + (size_t)BURST * CN;  // 14,680,064 (unscrambled y)
    float* fbuf  = buf3 + (size_t)BURST * CN;  // 229,376
    float* Mbuf  = fbuf + (size_t)BURST * NPIX; // 172,032
    float* Wcomb = Mbuf + 3 * 14 * 4096;    // 57,344
    float* cbv   = Wcomb + 64 * 896;        // 64

    const dim3 blk(256);

    // Folded fusion matrices
    precompute<<<43, 256, 0, stream>>>(fus_w, fus_b, Wc_w, Wc_b, Wh_w, Wh_b, Ww_w, Ww_b,
                                       Mbuf, Wcomb, cbv);

    // Residual path: out = W_comb @ x(viewed 896 x 16384) + combined bias
    gemm_nn<0, false, 0><<<dim3(256, 1, 1), blk, 0, stream>>>(
        Wcomb, x, out, cbv, 896, NPIX, 0, 0, 0, 896, NPIX);

    // ------------------- Part 1: channel attention -------------------
    gemm_nn<0, false, 0><<<dim3(256, 1, BURST), blk, 0, stream>>>(
        thc_w, x, buf1, thc_b, 64, NPIX, 0, CN, CN, 64, NPIX);
    gemm_nn<0, false, 0><<<dim3(256, 1, BURST), blk, 0, stream>>>(
        phc_w, x, buf2, phc_b, 64, NPIX, 0, CN, CN, 64, NPIX);
    hipMemsetAsync(fbuf, 0, (size_t)BURST * 4096 * sizeof(float), stream);
    gemm_nt<<<dim3(1, 16, BURST), blk, 0, stream>>>(
        buf1, buf2, fbuf, 16384, CN, NPIX, CN, NPIX, 4096, 64, 1);
    softmax_col64<<<BURST, 64, 0, stream>>>(fbuf);
    gemm_nn<0, false, 0><<<dim3(256, 1, BURST), blk, 0, stream>>>(
        gc_w, x, buf1, gc_b, 64, NPIX, 0, CN, CN, 64, NPIX);
    // y = f @ g, unscrambled (mode 1) into buf3
    gemm_nn<1, false, 0><<<dim3(256, 1, BURST), blk, 0, stream>>>(
        fbuf, buf1, buf3, nullptr, 64, NPIX, 4096, CN, CN, 64, NPIX);
    // out += sum_b M[0][b] @ y_unscr[b]
    gemm_nn<0, true, BURST><<<dim3(256, 1, 1), blk, 0, stream>>>(
        Mbuf, buf3, out, nullptr, 64, NPIX, 4096, CN, 0, 64, NPIX);

    // ------------------- Part 2: height attention -------------------
    gemm_nn<0, false, 0><<<dim3(256, 1, 1), blk, 0, stream>>>(
        thh_w, x, buf1, thh_b, 64, NPIX, 0, 0, 0, 64, NPIX);  // ref only
    gemm_nn<0, false, 0><<<dim3(256, 1, BURST), blk, 0, stream>>>(
        phh_w, x, buf2, phh_b, 64, NPIX, 0, CN, CN, 64, NPIX);
    hipMemsetAsync(fbuf, 0, (size_t)BURST * 16384 * sizeof(float), stream);
    gemm_nt<<<dim3(4, 8, BURST), blk, 0, stream>>>(
        buf1, buf2, fbuf, 8192, 0, 8192, CN, 8192, 16384, 128, 2);
    softmax_col128<<<BURST, 128, 0, stream>>>(fbuf);
    gemm_nn<0, false, 0><<<dim3(256, 1, BURST), blk, 0, stream>>>(
        gh_w, x, buf1, gh_b, 64, NPIX, 0, CN, CN, 64, NPIX);
    gemm_nn<2, false, 0><<<dim3(128, 2, BURST), blk, 0, stream>>>(
        fbuf, buf1, buf3, nullptr, 128, 8192, 16384, CN, CN, 128, 8192);
    gemm_nn<0, true, BURST><<<dim3(256, 1, 1), blk, 0, stream>>>(
        Mbuf + (size_t)14 * 4096, buf3, out, nullptr, 64, NPIX, 4096, CN, 0, 64, NPIX);

    // ------------------- Part 3: width attention -------------------
    gemm_nn<0, false, 0><<<dim3(256, 1, 1), blk, 0, stream>>>(
        thw_w, x, buf1, thw_b, 64, NPIX, 0, 0, 0, 64, NPIX);  // ref only
    gemm_nn<0, false, 0><<<dim3(256, 1, BURST), blk, 0, stream>>>(
        phw_w, x, buf2, phw_b, 64, NPIX, 0, CN, CN, 64, NPIX);
    hipMemsetAsync(fbuf, 0, (size_t)BURST * 16384 * sizeof(float), stream);
    gemm_nt<<<dim3(4, 8, BURST), blk, 0, stream>>>(
        buf1, buf2, fbuf, 8192, 0, 8192, CN, 8192, 16384, 128, 2);
    softmax_col128<<<BURST, 128, 0, stream>>>(fbuf);
    gemm_nn<0, false, 0><<<dim3(256, 1, BURST), blk, 0, stream>>>(
        gw_w, x, buf1, gw_b, 64, NPIX, 0, CN, CN, 64, NPIX);
    gemm_nn<2, false, 0><<<dim3(128, 2, BURST), blk, 0, stream>>>(
        fbuf, buf1, buf3, nullptr, 128, 8192, 16384, CN, CN, 128, 8192);
    gemm_nn<0, true, BURST><<<dim3(256, 1, 1), blk, 0, stream>>>(
        Mbuf + (size_t)28 * 4096, buf3, out, nullptr, 64, NPIX, 4096, CN, 0, 64, NPIX);

    // Final activation
    leaky_kernel<<<4096, 256, 0, stream>>>(out, 1048576);
}

// Round 2
// 664.126 us; speedup vs baseline: 2.5157x; 2.5157x over previous
//
#include <hip/hip_runtime.h>

#define NF 64
#define BURST 14
#define NPIX 16384
#define CN (NF * NPIX)
#define LP 72   // LDS pad stride in ushorts: bank stride 36 words -> 2-way max (free)

typedef short bf16x8 __attribute__((ext_vector_type(8)));
typedef float f32x4 __attribute__((ext_vector_type(4)));
typedef unsigned short us4 __attribute__((ext_vector_type(4)));

__device__ inline unsigned short f2bf(float f) {
    unsigned int u = __float_as_uint(f);
    return (unsigned short)((u + 0x7fffu + ((u >> 16) & 1u)) >> 16);
}

// ---------------------------------------------------------------------------
// Cast fp32 x -> bf16 (same layout), float4 -> 4x bf16 per thread
// ---------------------------------------------------------------------------
__global__ __launch_bounds__(256) void cast_x(const float4* __restrict__ X,
                                              unsigned short* __restrict__ O) {
    const int i = blockIdx.x * 256 + threadIdx.x;
    float4 v = X[i];
    us4 r;
    r.x = f2bf(v.x); r.y = f2bf(v.y); r.z = f2bf(v.z); r.w = f2bf(v.w);
    *(us4*)&O[(size_t)i * 4] = r;
}

// ---------------------------------------------------------------------------
// Precompute (fp32 math, bf16 outputs):
//  blocks 0..41 : M16[g][b][o][c'] = bf16( sum_c2 fus_w[o, g*896+b*64+c2] * Wg[c2,c'] )
//  block  42    : Wc16[o][bc] = bf16( sum_g fus_w[o, g*896+bc] );  cb fp32 combined bias
//  blocks 43..51: cast the 9 conv weights to bf16
// ---------------------------------------------------------------------------
__global__ __launch_bounds__(256) void precompute(
    const float* __restrict__ fus_w, const float* __restrict__ fus_b,
    const float* __restrict__ Wc, const float* __restrict__ bWc,
    const float* __restrict__ Wh, const float* __restrict__ bWh,
    const float* __restrict__ Ww, const float* __restrict__ bWw,
    unsigned short* __restrict__ M16, unsigned short* __restrict__ Wc16,
    float* __restrict__ cb,
    const float* __restrict__ w0, const float* __restrict__ w1, const float* __restrict__ w2,
    const float* __restrict__ w3, const float* __restrict__ w4, const float* __restrict__ w5,
    const float* __restrict__ w6, const float* __restrict__ w7, const float* __restrict__ w8,
    unsigned short* __restrict__ w16)
{
    const int blk = blockIdx.x, tid = threadIdx.x;
    if (blk < 42) {
        const int g = blk / 14, b = blk % 14;
        const float* Wg = (g == 0) ? Wc : (g == 1) ? Wh : Ww;
        unsigned short* Mout = M16 + ((size_t)g * 14 + b) * 4096;
        const int o = tid >> 2;
        for (int i = 0; i < 16; ++i) {
            const int cp = (tid & 3) * 16 + i;
            float s = 0.f;
            for (int c2 = 0; c2 < 64; ++c2)
                s += fus_w[o * 2688 + g * 896 + b * 64 + c2] * Wg[c2 * 64 + cp];
            Mout[o * 64 + cp] = f2bf(s);
        }
    } else if (blk == 42) {
        for (int e = tid; e < 64 * 896; e += 256) {
            const int o = e / 896, bc = e % 896;
            Wc16[e] = f2bf(fus_w[o * 2688 + bc] + fus_w[o * 2688 + 896 + bc] + fus_w[o * 2688 + 1792 + bc]);
        }
        if (tid < 64) {
            float s = fus_b[tid];
            for (int ch = 0; ch < 2688; ++ch) {
                const int g = ch / 896, c2 = ch % 64;
                const float* bg = (g == 0) ? bWc : (g == 1) ? bWh : bWw;
                s += fus_w[tid * 2688 + ch] * bg[c2];
            }
            cb[tid] = s;
        }
    } else {
        const int wi = blk - 43;
        const float* src = (wi == 0) ? w0 : (wi == 1) ? w1 : (wi == 2) ? w2 :
                           (wi == 3) ? w3 : (wi == 4) ? w4 : (wi == 5) ? w5 :
                           (wi == 6) ? w6 : (wi == 7) ? w7 : w8;
        unsigned short* dst = w16 + (size_t)wi * 4096;
        for (int e = tid; e < 4096; e += 256) dst[e] = f2bf(src[e]);
    }
}

// ---------------------------------------------------------------------------
// Conv 1x1 via MFMA: out[b][o][p] = bf16( sum_c W[o][c]*x[b][c][p] + bias[o] )
// m=o(64), n=p(tile 128), K=64.  grid (128, 1, nbatch), block 256.
// ---------------------------------------------------------------------------
__global__ __launch_bounds__(256) void conv_mfma(
    const unsigned short* __restrict__ W,   // 64x64 bf16 row-major [o][c]
    const unsigned short* __restrict__ X,   // [b][64][16384] bf16
    const float* __restrict__ bias,         // 64 fp32
    unsigned short* __restrict__ O)         // [b][64][16384] bf16
{
    __shared__ unsigned short Ws[64][LP];    // [o][c]
    __shared__ unsigned short Xs[128][LP];   // [p][c] (transposed tile)
    const int tid = threadIdx.x;
    const int p0 = blockIdx.x * 128;
    const size_t boff = (size_t)blockIdx.z * CN;

#pragma unroll
    for (int i = 0; i < 2; ++i) {
        const int ch = tid + 256 * i;          // 512 chunks of 8
        const int row = ch >> 3, c8 = (ch & 7) * 8;
        *(bf16x8*)&Ws[row][c8] = *(const bf16x8*)&W[row * 64 + c8];
    }
#pragma unroll
    for (int i = 0; i < 4; ++i) {
        const int id = tid + 256 * i;          // 1024 chunks of 8
        const int c = id & 63, p8 = (id >> 6) * 8;
        bf16x8 v = *(const bf16x8*)&X[boff + (size_t)c * NPIX + p0 + p8];
#pragma unroll
        for (int j = 0; j < 8; ++j) Xs[p8 + j][c] = (unsigned short)v[j];
    }
    __syncthreads();

    const int w = tid >> 6, l = tid & 63, lm = l & 15, q = l >> 4;
    const int mo = (w & 1) * 32;   // o offset (2 m-tiles per wave)
    const int no = (w >> 1) * 64;  // p offset (4 n-tiles per wave)
    f32x4 acc[2][4] = {};
#pragma unroll
    for (int ks = 0; ks < 2; ++ks) {
        const int c0 = ks * 32 + q * 8;
        bf16x8 a[2], bb[4];
#pragma unroll
        for (int mi = 0; mi < 2; ++mi) a[mi] = *(const bf16x8*)&Ws[mo + mi * 16 + lm][c0];
#pragma unroll
        for (int ni = 0; ni < 4; ++ni) bb[ni] = *(const bf16x8*)&Xs[no + ni * 16 + lm][c0];
#pragma unroll
        for (int mi = 0; mi < 2; ++mi)
#pragma unroll
            for (int ni = 0; ni < 4; ++ni)
                acc[mi][ni] = __builtin_amdgcn_mfma_f32_16x16x32_bf16(a[mi], bb[ni], acc[mi][ni], 0, 0, 0);
    }
#pragma unroll
    for (int mi = 0; mi < 2; ++mi)
#pragma unroll
        for (int r = 0; r < 4; ++r) {
            const int o = mo + mi * 16 + q * 4 + r;
            const float bv = bias[o];
#pragma unroll
            for (int ni = 0; ni < 4; ++ni) {
                const int p = p0 + no + ni * 16 + lm;
                O[boff + (size_t)o * NPIX + p] = f2bf(acc[mi][ni][r] + bv);
            }
        }
}

// ---------------------------------------------------------------------------
// NT f-GEMM via MFMA, frags direct from global, K-split, fp32 atomics:
// F[b][m][n] += sum_k A[b][m][k]*B[b][n][k].  Per-wave tile halves MH x NH.
// grid (1, ksplits, nbatch), block 256.
// ---------------------------------------------------------------------------
template <int MH, int NH>
__global__ __launch_bounds__(256) void fgemm_nt(
    const unsigned short* __restrict__ A, int aRS, long aBS,
    const unsigned short* __restrict__ B, int bRS, long bBS,
    float* __restrict__ F, int fBS, int fRS, int kchunk)
{
    const int tid = threadIdx.x;
    const int w = tid >> 6, l = tid & 63, lm = l & 15, q = l >> 4;
    const int b = blockIdx.z;
    const int k0 = blockIdx.y * kchunk;
    const unsigned short* Ab = A + (size_t)b * aBS;
    const unsigned short* Bb = B + (size_t)b * bBS;
    const int mo = (w & 1) * MH * 16;
    const int no = (w >> 1) * NH * 16;
    f32x4 acc[MH][NH] = {};
    const int ksteps = kchunk >> 5;
    for (int ks = 0; ks < ksteps; ++ks) {
        const int k = k0 + ks * 32 + q * 8;
        bf16x8 a[MH], bb[NH];
#pragma unroll
        for (int mi = 0; mi < MH; ++mi)
            a[mi] = *(const bf16x8*)&Ab[(size_t)(mo + mi * 16 + lm) * aRS + k];
#pragma unroll
        for (int ni = 0; ni < NH; ++ni)
            bb[ni] = *(const bf16x8*)&Bb[(size_t)(no + ni * 16 + lm) * bRS + k];
#pragma unroll
        for (int mi = 0; mi < MH; ++mi)
#pragma unroll
            for (int ni = 0; ni < NH; ++ni)
                acc[mi][ni] = __builtin_amdgcn_mfma_f32_16x16x32_bf16(a[mi], bb[ni], acc[mi][ni], 0, 0, 0);
    }
    float* Fb = F + (size_t)b * fBS;
#pragma unroll
    for (int mi = 0; mi < MH; ++mi)
#pragma unroll
        for (int r = 0; r < 4; ++r) {
            const int m = mo + mi * 16 + q * 4 + r;
#pragma unroll
            for (int ni = 0; ni < NH; ++ni)
                atomicAdd(&Fb[(size_t)m * fRS + no + ni * 16 + lm], acc[mi][ni][r]);
        }
}

// softmax over c for fixed (b,d): F[b*4096 + c*64 + d] -> bf16 F16 same layout
__global__ void softmax_col64(const float* __restrict__ F, unsigned short* __restrict__ F16)
{
    const float* Fb = F + (size_t)blockIdx.x * 4096;
    unsigned short* Ob = F16 + (size_t)blockIdx.x * 4096;
    const int d = threadIdx.x;
    float r[64];
    float mx = -1e30f;
#pragma unroll
    for (int c = 0; c < 64; ++c) { r[c] = Fb[c * 64 + d]; mx = fmaxf(mx, r[c]); }
    float s = 0.f;
#pragma unroll
    for (int c = 0; c < 64; ++c) { r[c] = __expf(r[c] - mx); s += r[c]; }
    const float inv = 1.f / s;
#pragma unroll
    for (int c = 0; c < 64; ++c) Ob[c * 64 + d] = f2bf(r[c] * inv);
}

// softmax over i for fixed (b,j): F[b*16384 + i*128 + j] -> bf16
__global__ void softmax_col128(const float* __restrict__ F, unsigned short* __restrict__ F16)
{
    const float* Fb = F + (size_t)blockIdx.x * 16384;
    unsigned short* Ob = F16 + (size_t)blockIdx.x * 16384;
    const int j = threadIdx.x;
    float mx = -1e30f;
    for (int i = 0; i < 128; ++i) mx = fmaxf(mx, Fb[i * 128 + j]);
    float s = 0.f;
    for (int i = 0; i < 128; ++i) s += __expf(Fb[i * 128 + j] - mx);
    const float inv = 1.f / s;
    for (int i = 0; i < 128; ++i) Ob[i * 128 + j] = f2bf(__expf(Fb[i * 128 + j] - mx) * inv);
}

// ---------------------------------------------------------------------------
// PV part 1: D[p][c] = sum_d g[d][p] * f[c][d];  store Y[b] at p*64+c (bf16)
// grid (128, 1, 14)
// ---------------------------------------------------------------------------
__global__ __launch_bounds__(256) void pv1(
    const unsigned short* __restrict__ G,   // [b][64][16384] c-major
    const unsigned short* __restrict__ F16, // [b][64][64]
    unsigned short* __restrict__ Y)
{
    __shared__ unsigned short Gs[128][LP];  // [p][d]
    __shared__ unsigned short Fs[64][LP];   // [c][d]
    const int tid = threadIdx.x;
    const int p0 = blockIdx.x * 128;
    const int b = blockIdx.z;
    const size_t boff = (size_t)b * CN;

#pragma unroll
    for (int i = 0; i < 2; ++i) {
        const int ch = tid + 256 * i;
        const int row = ch >> 3, c8 = (ch & 7) * 8;
        *(bf16x8*)&Fs[row][c8] = *(const bf16x8*)&F16[(size_t)b * 4096 + row * 64 + c8];
    }
#pragma unroll
    for (int i = 0; i < 4; ++i) {
        const int id = tid + 256 * i;
        const int d = id & 63, p8 = (id >> 6) * 8;
        bf16x8 v = *(const bf16x8*)&G[boff + (size_t)d * NPIX + p0 + p8];
#pragma unroll
        for (int j = 0; j < 8; ++j) Gs[p8 + j][d] = (unsigned short)v[j];
    }
    __syncthreads();

    const int w = tid >> 6, l = tid & 63, lm = l & 15, q = l >> 4;
    const int mo = (w & 1) * 64;   // p offset (4 m-tiles)
    const int no = (w >> 1) * 32;  // c offset (2 n-tiles)
    f32x4 acc[4][2] = {};
#pragma unroll
    for (int ks = 0; ks < 2; ++ks) {
        const int d0 = ks * 32 + q * 8;
        bf16x8 a[4], bb[2];
#pragma unroll
        for (int mi = 0; mi < 4; ++mi) a[mi] = *(const bf16x8*)&Gs[mo + mi * 16 + lm][d0];
#pragma unroll
        for (int ni = 0; ni < 2; ++ni) bb[ni] = *(const bf16x8*)&Fs[no + ni * 16 + lm][d0];
#pragma unroll
        for (int mi = 0; mi < 4; ++mi)
#pragma unroll
            for (int ni = 0; ni < 2; ++ni)
                acc[mi][ni] = __builtin_amdgcn_mfma_f32_16x16x32_bf16(a[mi], bb[ni], acc[mi][ni], 0, 0, 0);
    }
#pragma unroll
    for (int mi = 0; mi < 4; ++mi)
#pragma unroll
        for (int r = 0; r < 4; ++r) {
            const int p = p0 + mo + mi * 16 + q * 4 + r;
#pragma unroll
            for (int ni = 0; ni < 2; ++ni) {
                const int c = no + ni * 16 + lm;
                Y[boff + (size_t)p * 64 + c] = f2bf(acc[mi][ni][r]);
            }
        }
}

// ---------------------------------------------------------------------------
// PV parts 2/3: D[k][i] = sum_j gmat[j][k] * f[i][j]
// gmat = view rows stride 8192 (128 rows) on the c-major conv buffer.
// Store at ((k>>7)<<14) + (k&127)*128 + i   (c-major unscrambled flat)
// grid (128, 1, 14)   (k-tiles of 64)
// ---------------------------------------------------------------------------
__global__ __launch_bounds__(256) void pv2(
    const unsigned short* __restrict__ G,
    const unsigned short* __restrict__ F16, // [b][128][128]
    unsigned short* __restrict__ Y)
{
    __shared__ unsigned short Gs[64][136];  // [k][j], pad 136
    const int tid = threadIdx.x;
    const int k0 = blockIdx.x * 64;
    const int b = blockIdx.z;
    const size_t boff = (size_t)b * CN;

#pragma unroll
    for (int i = 0; i < 4; ++i) {
        const int id = tid + 256 * i;          // 1024 chunks of 8
        const int j = id & 127, k8 = (id >> 7) * 8;
        bf16x8 v = *(const bf16x8*)&G[boff + (size_t)j * 8192 + k0 + k8];
#pragma unroll
        for (int jj = 0; jj < 8; ++jj) Gs[k8 + jj][j] = (unsigned short)v[jj];
    }
    __syncthreads();

    const int w = tid >> 6, l = tid & 63, lm = l & 15, q = l >> 4;
    const int mo = (w & 1) * 32;   // k offset (2 m-tiles)
    const int no = (w >> 1) * 64;  // i offset (4 n-tiles)
    const unsigned short* Fb = F16 + (size_t)b * 16384;
    f32x4 acc[2][4] = {};
#pragma unroll
    for (int ks = 0; ks < 4; ++ks) {
        const int j0 = ks * 32 + q * 8;
        bf16x8 a[2], bb[4];
#pragma unroll
        for (int mi = 0; mi < 2; ++mi) a[mi] = *(const bf16x8*)&Gs[mo + mi * 16 + lm][j0];
#pragma unroll
        for (int ni = 0; ni < 4; ++ni)
            bb[ni] = *(const bf16x8*)&Fb[(size_t)(no + ni * 16 + lm) * 128 + j0];
#pragma unroll
        for (int mi = 0; mi < 2; ++mi)
#pragma unroll
            for (int ni = 0; ni < 4; ++ni)
                acc[mi][ni] = __builtin_amdgcn_mfma_f32_16x16x32_bf16(a[mi], bb[ni], acc[mi][ni], 0, 0, 0);
    }
#pragma unroll
    for (int mi = 0; mi < 2; ++mi)
#pragma unroll
        for (int r = 0; r < 4; ++r) {
            const int k = k0 + mo + mi * 16 + q * 4 + r;
#pragma unroll
            for (int ni = 0; ni < 4; ++ni) {
                const int ii = no + ni * 16 + lm;
                const size_t addr = (((size_t)(k >> 7)) << 14) + (size_t)(k & 127) * 128 + ii;
                Y[boff + addr] = f2bf(acc[mi][ni][r]);
            }
        }
}

// ---------------------------------------------------------------------------
// Fold: Out[o][pix] (fp32, atomic) += sum_{t in slice} Apair_t[o][c] * src_t[c][pix]
// Apairs: bf16, pair stride aPS, row stride aRS.  src: bf16 [c][16384] pairs.
// grid (128, 2): grid.y splits the 14 pairs into 7+7.
// ---------------------------------------------------------------------------
__global__ __launch_bounds__(256) void fold_mfma(
    const unsigned short* __restrict__ Ap, long aPS, int aRS,
    const unsigned short* __restrict__ S, long sPS,
    float* __restrict__ Out)
{
    __shared__ unsigned short As[64][LP];
    __shared__ unsigned short Ss[128][LP];
    const int tid = threadIdx.x;
    const int p0 = blockIdx.x * 128;
    const int t0 = blockIdx.y * 7;
    const int w = tid >> 6, l = tid & 63, lm = l & 15, q = l >> 4;
    const int mo = (w & 1) * 32;   // o offset
    const int no = (w >> 1) * 64;  // pix offset
    f32x4 acc[2][4] = {};

    for (int t = t0; t < t0 + 7; ++t) {
        __syncthreads();
#pragma unroll
        for (int i = 0; i < 2; ++i) {
            const int ch = tid + 256 * i;
            const int row = ch >> 3, c8 = (ch & 7) * 8;
            *(bf16x8*)&As[row][c8] = *(const bf16x8*)&Ap[(size_t)t * aPS + (size_t)row * aRS + c8];
        }
#pragma unroll
        for (int i = 0; i < 4; ++i) {
            const int id = tid + 256 * i;
            const int c = id & 63, p8 = (id >> 6) * 8;
            bf16x8 v = *(const bf16x8*)&S[(size_t)t * sPS + (size_t)c * NPIX + p0 + p8];
#pragma unroll
            for (int j = 0; j < 8; ++j) Ss[p8 + j][c] = (unsigned short)v[j];
        }
        __syncthreads();
#pragma unroll
        for (int ks = 0; ks < 2; ++ks) {
            const int c0 = ks * 32 + q * 8;
            bf16x8 a[2], bb[4];
#pragma unroll
            for (int mi = 0; mi < 2; ++mi) a[mi] = *(const bf16x8*)&As[mo + mi * 16 + lm][c0];
#pragma unroll
            for (int ni = 0; ni < 4; ++ni) bb[ni] = *(const bf16x8*)&Ss[no + ni * 16 + lm][c0];
#pragma unroll
            for (int mi = 0; mi < 2; ++mi)
#pragma unroll
                for (int ni = 0; ni < 4; ++ni)
                    acc[mi][ni] = __builtin_amdgcn_mfma_f32_16x16x32_bf16(a[mi], bb[ni], acc[mi][ni], 0, 0, 0);
        }
    }
#pragma unroll
    for (int mi = 0; mi < 2; ++mi)
#pragma unroll
        for (int r = 0; r < 4; ++r) {
            const int o = mo + mi * 16 + q * 4 + r;
#pragma unroll
            for (int ni = 0; ni < 4; ++ni) {
                const int pix = p0 + no + ni * 16 + lm;
                atomicAdd(&Out[(size_t)o * NPIX + pix], acc[mi][ni][r]);
            }
        }
}

// out = leaky(out + cb[o]), float4 per thread
__global__ __launch_bounds__(256) void leaky_cb(float* __restrict__ O, const float* __restrict__ cb)
{
    const int i = blockIdx.x * 256 + threadIdx.x;
    float4 v = ((float4*)O)[i];
    const float b = cb[(i * 4) >> 14];
    v.x += b; v.y += b; v.z += b; v.w += b;
    v.x = v.x >= 0.f ? v.x : 0.2f * v.x;
    v.y = v.y >= 0.f ? v.y : 0.2f * v.y;
    v.z = v.z >= 0.f ? v.z : 0.2f * v.z;
    v.w = v.w >= 0.f ? v.w : 0.2f * v.w;
    ((float4*)O)[i] = v;
}

extern "C" void kernel_launch(void* const* d_in, const int* in_sizes, int n_in,
                              void* d_out, int out_size, void* d_ws, size_t ws_size,
                              hipStream_t stream)
{
    const float* x     = (const float*)d_in[0];
    const float* gc_w  = (const float*)d_in[1];
    const float* gc_b  = (const float*)d_in[2];
    const float* thc_w = (const float*)d_in[3];
    const float* thc_b = (const float*)d_in[4];
    const float* phc_w = (const float*)d_in[5];
    const float* phc_b = (const float*)d_in[6];
    const float* Wc_w  = (const float*)d_in[7];
    const float* Wc_b  = (const float*)d_in[8];
    const float* gh_w  = (const float*)d_in[9];
    const float* gh_b  = (const float*)d_in[10];
    const float* thh_w = (const float*)d_in[11];
    const float* thh_b = (const float*)d_in[12];
    const float* phh_w = (const float*)d_in[13];
    const float* phh_b = (const float*)d_in[14];
    const float* Wh_w  = (const float*)d_in[15];
    const float* Wh_b  = (const float*)d_in[16];
    const float* gw_w  = (const float*)d_in[17];
    const float* gw_b  = (const float*)d_in[18];
    const float* thw_w = (const float*)d_in[19];
    const float* thw_b = (const float*)d_in[20];
    const float* phw_w = (const float*)d_in[21];
    const float* phw_b = (const float*)d_in[22];
    const float* Ww_w  = (const float*)d_in[23];
    const float* Ww_b  = (const float*)d_in[24];
    const float* fus_w = (const float*)d_in[25];
    const float* fus_b = (const float*)d_in[26];

    float* out = (float*)d_out;

    char* p = (char*)d_ws;
    unsigned short* xb   = (unsigned short*)p; p += (size_t)BURST * CN * 2;
    unsigned short* bufA = (unsigned short*)p; p += (size_t)BURST * CN * 2;
    unsigned short* bufB = (unsigned short*)p; p += (size_t)BURST * CN * 2;
    unsigned short* bufY = (unsigned short*)p; p += (size_t)BURST * CN * 2;
    float*          fbuf = (float*)p;          p += (size_t)BURST * NPIX * 4;
    unsigned short* f16  = (unsigned short*)p; p += (size_t)BURST * NPIX * 2;
    unsigned short* w16  = (unsigned short*)p; p += (size_t)9 * 4096 * 2;
    unsigned short* M16  = (unsigned short*)p; p += (size_t)42 * 4096 * 2;
    unsigned short* Wc16 = (unsigned short*)p; p += (size_t)64 * 896 * 2;
    float*          cbv  = (float*)p;          p += 256;

    cast_x<<<14336, 256, 0, stream>>>((const float4*)x, xb);
    precompute<<<52, 256, 0, stream>>>(fus_w, fus_b, Wc_w, Wc_b, Wh_w, Wh_b, Ww_w, Ww_b,
                                       M16, Wc16, cbv,
                                       thc_w, phc_w, gc_w, thh_w, phh_w, gh_w, thw_w, phw_w, gw_w,
                                       w16);
    hipMemsetAsync(out, 0, (size_t)NF * NPIX * 4, stream);

    // Residual: out += Wcomb @ x(896x16384)
    fold_mfma<<<dim3(128, 2), 256, 0, stream>>>(Wc16, 64, 896, xb, CN, out);

    // ---------------- Part 1: channel attention ----------------
    conv_mfma<<<dim3(128, 1, BURST), 256, 0, stream>>>(w16 + 0 * 4096, xb, thc_b, bufA);
    conv_mfma<<<dim3(128, 1, BURST), 256, 0, stream>>>(w16 + 1 * 4096, xb, phc_b, bufB);
    hipMemsetAsync(fbuf, 0, (size_t)BURST * 4096 * 4, stream);
    fgemm_nt<2, 2><<<dim3(1, 32, BURST), 256, 0, stream>>>(
        bufA, NPIX, CN, bufB, NPIX, CN, fbuf, 4096, 64, 512);
    softmax_col64<<<BURST, 64, 0, stream>>>(fbuf, f16);
    conv_mfma<<<dim3(128, 1, BURST), 256, 0, stream>>>(w16 + 2 * 4096, xb, gc_b, bufA);
    pv1<<<dim3(128, 1, BURST), 256, 0, stream>>>(bufA, f16, bufY);
    fold_mfma<<<dim3(128, 2), 256, 0, stream>>>(M16, 4096, 64, bufY, CN, out);

    // ---------------- Part 2: height attention ----------------
    conv_mfma<<<dim3(128, 1, 1), 256, 0, stream>>>(w16 + 3 * 4096, xb, thh_b, bufA);
    conv_mfma<<<dim3(128, 1, BURST), 256, 0, stream>>>(w16 + 4 * 4096, xb, phh_b, bufB);
    hipMemsetAsync(fbuf, 0, (size_t)BURST * NPIX * 4, stream);
    fgemm_nt<4, 4><<<dim3(1, 32, BURST), 256, 0, stream>>>(
        bufA, 8192, 0, bufB, 8192, CN, fbuf, NPIX, 128, 256);
    softmax_col128<<<BURST, 128, 0, stream>>>(fbuf, f16);
    conv_mfma<<<dim3(128, 1, BURST), 256, 0, stream>>>(w16 + 5 * 4096, xb, gh_b, bufA);
    pv2<<<dim3(128, 1, BURST), 256, 0, stream>>>(bufA, f16, bufY);
    fold_mfma<<<dim3(128, 2), 256, 0, stream>>>(M16 + (size_t)14 * 4096, 4096, 64, bufY, CN, out);

    // ---------------- Part 3: width attention ----------------
    conv_mfma<<<dim3(128, 1, 1), 256, 0, stream>>>(w16 + 6 * 4096, xb, thw_b, bufA);
    conv_mfma<<<dim3(128, 1, BURST), 256, 0, stream>>>(w16 + 7 * 4096, xb, phw_b, bufB);
    hipMemsetAsync(fbuf, 0, (size_t)BURST * NPIX * 4, stream);
    fgemm_nt<4, 4><<<dim3(1, 32, BURST), 256, 0, stream>>>(
        bufA, 8192, 0, bufB, 8192, CN, fbuf, NPIX, 128, 256);
    softmax_col128<<<BURST, 128, 0, stream>>>(fbuf, f16);
    conv_mfma<<<dim3(128, 1, BURST), 256, 0, stream>>>(w16 + 8 * 4096, xb, gw_b, bufA);
    pv2<<<dim3(128, 1, BURST), 256, 0, stream>>>(bufA, f16, bufY);
    fold_mfma<<<dim3(128, 2), 256, 0, stream>>>(M16 + (size_t)28 * 4096, 4096, 64, bufY, CN, out);

    leaky_cb<<<1024, 256, 0, stream>>>(out, cbv);
}

// Round 3
// 577.834 us; speedup vs baseline: 2.8914x; 1.1493x over previous
//
#include <hip/hip_runtime.h>

#define NF 64
#define BURST 14
#define NPIX 16384
#define CN (NF * NPIX)
#define LP 72

typedef short bf16x8 __attribute__((ext_vector_type(8)));
typedef float f32x4 __attribute__((ext_vector_type(4)));
typedef unsigned short us4 __attribute__((ext_vector_type(4)));

__device__ inline unsigned short f2bf(float f) {
    unsigned int u = __float_as_uint(f);
    return (unsigned short)((u + 0x7fffu + ((u >> 16) & 1u)) >> 16);
}

// ---------------------------------------------------------------------------
// x fp32 [b][c][pix]  ->  xT bf16 [b][pix][c]   (LDS-tiled transpose)
// grid (128, 14), block 256
// ---------------------------------------------------------------------------
__global__ __launch_bounds__(256) void cast_xT(const float* __restrict__ X,
                                               unsigned short* __restrict__ XT)
{
    __shared__ unsigned short Xs[128][LP];
    const int tid = threadIdx.x;
    const int p0 = blockIdx.x * 128;
    const size_t boff = (size_t)blockIdx.y * CN;
#pragma unroll
    for (int i = 0; i < 8; ++i) {
        const int id = tid + 256 * i;            // 2048 float4 chunks
        const int c = id >> 5, p4 = (id & 31) * 4;
        float4 v = *(const float4*)&X[boff + (size_t)c * NPIX + p0 + p4];
        Xs[p4 + 0][c] = f2bf(v.x); Xs[p4 + 1][c] = f2bf(v.y);
        Xs[p4 + 2][c] = f2bf(v.z); Xs[p4 + 3][c] = f2bf(v.w);
    }
    __syncthreads();
#pragma unroll
    for (int i = 0; i < 4; ++i) {
        const int id = tid + 256 * i;            // 1024 16B chunks
        const int row = id >> 3, c8 = (id & 7) * 8;
        *(bf16x8*)&XT[boff + (size_t)(p0 + row) * 64 + c8] = *(const bf16x8*)&Xs[row][c8];
    }
}

// ---------------------------------------------------------------------------
// Precompute, fully parallel:
//  blocks 0..41: M16[g][b] = bf16(Fsub @ Wg)  (LDS-staged 64x64x64)
//  block 42: Wc16 = bf16(sum_g fus slices)
//  block 43: cb[o] = fus_b[o] + sum_ch fus_w[o][ch]*bg[ch%64]  (wave-parallel)
//  blocks 44..52: conv weight casts;  block 53: bias pack
// ---------------------------------------------------------------------------
__global__ __launch_bounds__(256) void precompute(
    const float* __restrict__ fus_w, const float* __restrict__ fus_b,
    const float* __restrict__ Wc, const float* __restrict__ bWc,
    const float* __restrict__ Wh, const float* __restrict__ bWh,
    const float* __restrict__ Ww, const float* __restrict__ bWw,
    unsigned short* __restrict__ M16, unsigned short* __restrict__ Wc16,
    float* __restrict__ cb,
    const float* __restrict__ w0, const float* __restrict__ w1, const float* __restrict__ w2,
    const float* __restrict__ w3, const float* __restrict__ w4, const float* __restrict__ w5,
    const float* __restrict__ w6, const float* __restrict__ w7, const float* __restrict__ w8,
    const float* __restrict__ b0, const float* __restrict__ b1, const float* __restrict__ b2,
    const float* __restrict__ b3, const float* __restrict__ b4, const float* __restrict__ b5,
    const float* __restrict__ b6, const float* __restrict__ b7, const float* __restrict__ b8,
    unsigned short* __restrict__ w16, float* __restrict__ bias9)
{
    const int blk = blockIdx.x, tid = threadIdx.x;
    if (blk < 42) {
        __shared__ float Fl[64][65];
        __shared__ float Wl[64][65];
        const int g = blk / 14, b = blk % 14;
        const float* Wg = (g == 0) ? Wc : (g == 1) ? Wh : Ww;
#pragma unroll
        for (int i = 0; i < 4; ++i) {
            const int id = tid + 256 * i;        // 1024 float4
            const int r = id >> 4, c4 = (id & 15) * 4;
            float4 v = *(const float4*)&fus_w[r * 2688 + g * 896 + b * 64 + c4];
            Fl[r][c4] = v.x; Fl[r][c4 + 1] = v.y; Fl[r][c4 + 2] = v.z; Fl[r][c4 + 3] = v.w;
            float4 u = *(const float4*)&Wg[r * 64 + c4];
            Wl[r][c4] = u.x; Wl[r][c4 + 1] = u.y; Wl[r][c4 + 2] = u.z; Wl[r][c4 + 3] = u.w;
        }
        __syncthreads();
        const int o = tid & 63, qq = tid >> 6;
        float s[16];
#pragma unroll
        for (int i = 0; i < 16; ++i) s[i] = 0.f;
        for (int c2 = 0; c2 < 64; ++c2) {
            const float fv = Fl[o][c2];
#pragma unroll
            for (int i = 0; i < 16; ++i) s[i] += fv * Wl[c2][qq * 16 + i];
        }
        unsigned short* Mout = M16 + (size_t)blk * 4096;
#pragma unroll
        for (int i = 0; i < 16; i += 4) {
            us4 r4; r4.x = f2bf(s[i]); r4.y = f2bf(s[i + 1]); r4.z = f2bf(s[i + 2]); r4.w = f2bf(s[i + 3]);
            *(us4*)&Mout[o * 64 + qq * 16 + i] = r4;
        }
    } else if (blk == 42) {
        for (int e = tid; e < 64 * 896; e += 256) {
            const int o = e / 896, bc = e % 896;
            Wc16[e] = f2bf(fus_w[o * 2688 + bc] + fus_w[o * 2688 + 896 + bc] + fus_w[o * 2688 + 1792 + bc]);
        }
    } else if (blk == 43) {
        __shared__ float red[256];
        const int o = tid & 63, qq = tid >> 6;
        float s = 0.f;
        for (int t = 0; t < 672; ++t) {
            const int ch = qq * 672 + t;
            const int g = ch / 896, c2 = ch & 63;
            const float bg = (g == 0) ? bWc[c2] : (g == 1) ? bWh[c2] : bWw[c2];
            s += fus_w[o * 2688 + ch] * bg;
        }
        red[tid] = s;
        __syncthreads();
        if (tid < 64) cb[tid] = fus_b[tid] + red[tid] + red[64 + tid] + red[128 + tid] + red[192 + tid];
    } else if (blk < 53) {
        const int wi = blk - 44;
        const float* src = (wi == 0) ? w0 : (wi == 1) ? w1 : (wi == 2) ? w2 :
                           (wi == 3) ? w3 : (wi == 4) ? w4 : (wi == 5) ? w5 :
                           (wi == 6) ? w6 : (wi == 7) ? w7 : w8;
        unsigned short* dst = w16 + (size_t)wi * 4096;
        for (int e = tid; e < 4096; e += 256) dst[e] = f2bf(src[e]);
    } else {
        if (tid < 64) {
            bias9[0 * 64 + tid] = b0[tid]; bias9[1 * 64 + tid] = b1[tid]; bias9[2 * 64 + tid] = b2[tid];
            bias9[3 * 64 + tid] = b3[tid]; bias9[4 * 64 + tid] = b4[tid]; bias9[5 * 64 + tid] = b5[tid];
            bias9[6 * 64 + tid] = b6[tid]; bias9[7 * 64 + tid] = b7[tid]; bias9[8 * 64 + tid] = b8[tid];
        }
    }
}

// ---------------------------------------------------------------------------
// Residual fold, LDS-free: Out[o][pix] = sum_{b,c} Wc16[o][b*64+c] xT[b][pix][c]
// grid (128), block 256.  Plain stores (first writer of out).
// ---------------------------------------------------------------------------
__global__ __launch_bounds__(256) void fold_res(
    const unsigned short* __restrict__ Wcomb, const unsigned short* __restrict__ XT,
    float* __restrict__ Out)
{
    const int tid = threadIdx.x;
    const int w = tid >> 6, l = tid & 63, lm = l & 15, q = l >> 4;
    const int p0 = blockIdx.x * 128 + (w >> 1) * 64;
    const int oh = (w & 1) * 32;
    f32x4 acc[2][4] = {};
    for (int b = 0; b < 14; ++b) {
#pragma unroll
        for (int ks = 0; ks < 2; ++ks) {
            const int c0 = ks * 32 + q * 8;
            bf16x8 a[2], bb[4];
#pragma unroll
            for (int mi = 0; mi < 2; ++mi)
                a[mi] = *(const bf16x8*)&Wcomb[(oh + mi * 16 + lm) * 896 + b * 64 + c0];
#pragma unroll
            for (int ni = 0; ni < 4; ++ni)
                bb[ni] = *(const bf16x8*)&XT[(size_t)b * CN + (size_t)(p0 + ni * 16 + lm) * 64 + c0];
#pragma unroll
            for (int mi = 0; mi < 2; ++mi)
#pragma unroll
                for (int ni = 0; ni < 4; ++ni)
                    acc[mi][ni] = __builtin_amdgcn_mfma_f32_16x16x32_bf16(a[mi], bb[ni], acc[mi][ni], 0, 0, 0);
        }
    }
#pragma unroll
    for (int mi = 0; mi < 2; ++mi)
#pragma unroll
        for (int r = 0; r < 4; ++r) {
            const int o = oh + mi * 16 + q * 4 + r;
#pragma unroll
            for (int ni = 0; ni < 4; ++ni)
                Out[(size_t)o * NPIX + p0 + ni * 16 + lm] = acc[mi][ni][r];
        }
}

// ---------------------------------------------------------------------------
// Batched th/ph convs (STD layout [o][pix]), LDS-free.
// grid (64, 1, 58), block 256.  D[m=o][n=p].
// ---------------------------------------------------------------------------
__global__ __launch_bounds__(256) void convA(
    const unsigned short* __restrict__ XT, const unsigned short* __restrict__ W16,
    const float* __restrict__ bias9,
    unsigned short* __restrict__ th1, unsigned short* __restrict__ ph1,
    unsigned short* __restrict__ th2, unsigned short* __restrict__ ph2,
    unsigned short* __restrict__ th3, unsigned short* __restrict__ ph3)
{
    const int z = blockIdx.z;
    int wi, b; unsigned short* dst;
    if (z < 14)      { wi = 0; b = z;      dst = th1; }
    else if (z < 28) { wi = 1; b = z - 14; dst = ph1; }
    else if (z < 29) { wi = 3; b = 0;      dst = th2; }
    else if (z < 43) { wi = 4; b = z - 29; dst = ph2; }
    else if (z < 44) { wi = 6; b = 0;      dst = th3; }
    else             { wi = 7; b = z - 44; dst = ph3; }
    dst += (size_t)b * CN;
    const unsigned short* Wp = W16 + wi * 4096;
    const unsigned short* Xb = XT + (size_t)b * CN;
    const int tid = threadIdx.x;
    const int w = tid >> 6, l = tid & 63, lm = l & 15, q = l >> 4;
    const int p0 = blockIdx.x * 256 + w * 64;
    f32x4 acc[4][4] = {};
#pragma unroll
    for (int ks = 0; ks < 2; ++ks) {
        const int c0 = ks * 32 + q * 8;
        bf16x8 a[4], bb[4];
#pragma unroll
        for (int mi = 0; mi < 4; ++mi) a[mi] = *(const bf16x8*)&Wp[(mi * 16 + lm) * 64 + c0];
#pragma unroll
        for (int ni = 0; ni < 4; ++ni) bb[ni] = *(const bf16x8*)&Xb[(size_t)(p0 + ni * 16 + lm) * 64 + c0];
#pragma unroll
        for (int mi = 0; mi < 4; ++mi)
#pragma unroll
            for (int ni = 0; ni < 4; ++ni)
                acc[mi][ni] = __builtin_amdgcn_mfma_f32_16x16x32_bf16(a[mi], bb[ni], acc[mi][ni], 0, 0, 0);
    }
    const float* bv = bias9 + wi * 64;
#pragma unroll
    for (int mi = 0; mi < 4; ++mi)
#pragma unroll
        for (int r = 0; r < 4; ++r) {
            const int o = mi * 16 + q * 4 + r;
            const float bo = bv[o];
#pragma unroll
            for (int ni = 0; ni < 4; ++ni)
                dst[(size_t)o * NPIX + p0 + ni * 16 + lm] = f2bf(acc[mi][ni][r] + bo);
        }
}

// ---------------------------------------------------------------------------
// Batched g convs, transposed outputs, LDS-free.  D[m=p][n=o].
// mode 0 (part1): gT[p*64+o].  mode 1 (parts 2/3): G2T[(p&8191)*128 + o*2 + (p>>13)]
// grid (64, 1, 42), block 256.
// ---------------------------------------------------------------------------
__global__ __launch_bounds__(256) void convB(
    const unsigned short* __restrict__ XT, const unsigned short* __restrict__ W16,
    const float* __restrict__ bias9,
    unsigned short* __restrict__ g1, unsigned short* __restrict__ g2,
    unsigned short* __restrict__ g3)
{
    const int z = blockIdx.z;
    int wi, b, mode; unsigned short* dst;
    if (z < 14)      { wi = 2; b = z;      dst = g1; mode = 0; }
    else if (z < 28) { wi = 5; b = z - 14; dst = g2; mode = 1; }
    else             { wi = 8; b = z - 28; dst = g3; mode = 1; }
    dst += (size_t)b * CN;
    const unsigned short* Wp = W16 + wi * 4096;
    const unsigned short* Xb = XT + (size_t)b * CN;
    const int tid = threadIdx.x;
    const int w = tid >> 6, l = tid & 63, lm = l & 15, q = l >> 4;
    const int p0 = blockIdx.x * 256 + w * 64;
    f32x4 acc[4][4] = {};
#pragma unroll
    for (int ks = 0; ks < 2; ++ks) {
        const int c0 = ks * 32 + q * 8;
        bf16x8 a[4], bb[4];
#pragma unroll
        for (int mi = 0; mi < 4; ++mi) a[mi] = *(const bf16x8*)&Xb[(size_t)(p0 + mi * 16 + lm) * 64 + c0];
#pragma unroll
        for (int ni = 0; ni < 4; ++ni) bb[ni] = *(const bf16x8*)&Wp[(ni * 16 + lm) * 64 + c0];
#pragma unroll
        for (int mi = 0; mi < 4; ++mi)
#pragma unroll
            for (int ni = 0; ni < 4; ++ni)
                acc[mi][ni] = __builtin_amdgcn_mfma_f32_16x16x32_bf16(a[mi], bb[ni], acc[mi][ni], 0, 0, 0);
    }
    const float* bv = bias9 + wi * 64;
#pragma unroll
    for (int mi = 0; mi < 4; ++mi)
#pragma unroll
        for (int r = 0; r < 4; ++r) {
            const int p = p0 + mi * 16 + q * 4 + r;
#pragma unroll
            for (int ni = 0; ni < 4; ++ni) {
                const int o = ni * 16 + lm;
                const unsigned short v = f2bf(acc[mi][ni][r] + bv[o]);
                if (mode == 0) dst[(size_t)p * 64 + o] = v;
                else dst[(size_t)(p & 8191) * 128 + o * 2 + (p >> 13)] = v;
            }
        }
}

// ---------------------------------------------------------------------------
// NT f-GEMM, frags direct from global, K-split, fp32 atomics (round-1, proven)
// ---------------------------------------------------------------------------
template <int MH, int NH>
__global__ __launch_bounds__(256) void fgemm_nt(
    const unsigned short* __restrict__ A, int aRS, long aBS,
    const unsigned short* __restrict__ B, int bRS, long bBS,
    float* __restrict__ F, int fBS, int fRS, int kchunk)
{
    const int tid = threadIdx.x;
    const int w = tid >> 6, l = tid & 63, lm = l & 15, q = l >> 4;
    const int b = blockIdx.z;
    const int k0 = blockIdx.y * kchunk;
    const unsigned short* Ab = A + (size_t)b * aBS;
    const unsigned short* Bb = B + (size_t)b * bBS;
    const int mo = (w & 1) * MH * 16;
    const int no = (w >> 1) * NH * 16;
    f32x4 acc[MH][NH] = {};
    const int ksteps = kchunk >> 5;
    for (int ks = 0; ks < ksteps; ++ks) {
        const int k = k0 + ks * 32 + q * 8;
        bf16x8 a[MH], bb[NH];
#pragma unroll
        for (int mi = 0; mi < MH; ++mi)
            a[mi] = *(const bf16x8*)&Ab[(size_t)(mo + mi * 16 + lm) * aRS + k];
#pragma unroll
        for (int ni = 0; ni < NH; ++ni)
            bb[ni] = *(const bf16x8*)&Bb[(size_t)(no + ni * 16 + lm) * bRS + k];
#pragma unroll
        for (int mi = 0; mi < MH; ++mi)
#pragma unroll
            for (int ni = 0; ni < NH; ++ni)
                acc[mi][ni] = __builtin_amdgcn_mfma_f32_16x16x32_bf16(a[mi], bb[ni], acc[mi][ni], 0, 0, 0);
    }
    float* Fb = F + (size_t)b * fBS;
#pragma unroll
    for (int mi = 0; mi < MH; ++mi)
#pragma unroll
        for (int r = 0; r < 4; ++r) {
            const int m = mo + mi * 16 + q * 4 + r;
#pragma unroll
            for (int ni = 0; ni < NH; ++ni)
                atomicAdd(&Fb[(size_t)m * fRS + no + ni * 16 + lm], acc[mi][ni][r]);
        }
}

// softmax over c for fixed (b,d): F[b*4096 + c*64 + d] -> bf16
__global__ __launch_bounds__(256) void softmax64(const float* __restrict__ F,
                                                 unsigned short* __restrict__ O)
{
    __shared__ float red[256];
    __shared__ float mxA[64], invA[64];
    const int b = blockIdx.x, tid = threadIdx.x;
    const float* Fb = F + (size_t)b * 4096;
    const int d = tid & 63, qq = tid >> 6;
    float mx = -1e30f;
    for (int c = qq * 16; c < qq * 16 + 16; ++c) mx = fmaxf(mx, Fb[c * 64 + d]);
    red[tid] = mx;
    __syncthreads();
    if (tid < 64) mxA[tid] = fmaxf(fmaxf(red[tid], red[64 + tid]), fmaxf(red[128 + tid], red[192 + tid]));
    __syncthreads();
    const float m = mxA[d];
    float s = 0.f;
    for (int c = qq * 16; c < qq * 16 + 16; ++c) s += __expf(Fb[c * 64 + d] - m);
    red[tid] = s;
    __syncthreads();
    if (tid < 64) invA[tid] = 1.f / (red[tid] + red[64 + tid] + red[128 + tid] + red[192 + tid]);
    __syncthreads();
    unsigned short* Ob = O + (size_t)b * 4096;
    const int e0 = tid * 16;
#pragma unroll
    for (int i = 0; i < 16; i += 4) {
        us4 r4;
        const int dd = (e0 & 63) + i;
        r4.x = f2bf(__expf(Fb[e0 + i] - mxA[dd]) * invA[dd]);
        r4.y = f2bf(__expf(Fb[e0 + i + 1] - mxA[dd + 1]) * invA[dd + 1]);
        r4.z = f2bf(__expf(Fb[e0 + i + 2] - mxA[dd + 2]) * invA[dd + 2]);
        r4.w = f2bf(__expf(Fb[e0 + i + 3] - mxA[dd + 3]) * invA[dd + 3]);
        *(us4*)&Ob[e0 + i] = r4;
    }
}

// softmax over i for fixed (b,j): F[b*16384 + i*128 + j] -> bf16
__global__ __launch_bounds__(256) void softmax128(const float* __restrict__ F,
                                                  unsigned short* __restrict__ O)
{
    __shared__ float red[256];
    __shared__ float mxA[128], invA[128];
    const int b = blockIdx.x, tid = threadIdx.x;
    const float* Fb = F + (size_t)b * 16384;
    const int j = tid & 127, ih = tid >> 7;
    float mx = -1e30f;
    for (int i = ih * 64; i < ih * 64 + 64; ++i) mx = fmaxf(mx, Fb[i * 128 + j]);
    red[tid] = mx;
    __syncthreads();
    if (tid < 128) mxA[tid] = fmaxf(red[tid], red[128 + tid]);
    __syncthreads();
    const float m = mxA[j];
    float s = 0.f;
    for (int i = ih * 64; i < ih * 64 + 64; ++i) s += __expf(Fb[i * 128 + j] - m);
    red[tid] = s;
    __syncthreads();
    if (tid < 128) invA[tid] = 1.f / (red[tid] + red[128 + tid]);
    __syncthreads();
    unsigned short* Ob = O + (size_t)b * 16384;
    const int e0 = tid * 64;
    for (int i = 0; i < 64; i += 4) {
        us4 r4;
        const int jj = (e0 & 127) + i;
        r4.x = f2bf(__expf(Fb[e0 + i] - mxA[jj]) * invA[jj]);
        r4.y = f2bf(__expf(Fb[e0 + i + 1] - mxA[jj + 1]) * invA[jj + 1]);
        r4.z = f2bf(__expf(Fb[e0 + i + 2] - mxA[jj + 2]) * invA[jj + 2]);
        r4.w = f2bf(__expf(Fb[e0 + i + 3] - mxA[jj + 3]) * invA[jj + 3]);
        *(us4*)&Ob[e0 + i] = r4;
    }
}

// ---------------------------------------------------------------------------
// pv1, LDS-free: Y[p*64+c] = sum_d gT[p][d] f[c][d].  grid (64,1,14)
// ---------------------------------------------------------------------------
__global__ __launch_bounds__(256) void pv1(
    const unsigned short* __restrict__ GT, const unsigned short* __restrict__ F16,
    unsigned short* __restrict__ Y)
{
    const int tid = threadIdx.x;
    const int w = tid >> 6, l = tid & 63, lm = l & 15, q = l >> 4;
    const int b = blockIdx.z;
    const int p0 = blockIdx.x * 256 + w * 64;
    const unsigned short* Gb = GT + (size_t)b * CN;
    const unsigned short* Fb = F16 + (size_t)b * 4096;
    f32x4 acc[4][4] = {};
#pragma unroll
    for (int ks = 0; ks < 2; ++ks) {
        const int d0 = ks * 32 + q * 8;
        bf16x8 a[4], bb[4];
#pragma unroll
        for (int mi = 0; mi < 4; ++mi) a[mi] = *(const bf16x8*)&Gb[(size_t)(p0 + mi * 16 + lm) * 64 + d0];
#pragma unroll
        for (int ni = 0; ni < 4; ++ni) bb[ni] = *(const bf16x8*)&Fb[(ni * 16 + lm) * 64 + d0];
#pragma unroll
        for (int mi = 0; mi < 4; ++mi)
#pragma unroll
            for (int ni = 0; ni < 4; ++ni)
                acc[mi][ni] = __builtin_amdgcn_mfma_f32_16x16x32_bf16(a[mi], bb[ni], acc[mi][ni], 0, 0, 0);
    }
    unsigned short* Yb = Y + (size_t)b * CN;
#pragma unroll
    for (int mi = 0; mi < 4; ++mi)
#pragma unroll
        for (int r = 0; r < 4; ++r) {
            const int p = p0 + mi * 16 + q * 4 + r;
#pragma unroll
            for (int ni = 0; ni < 4; ++ni)
                Yb[(size_t)p * 64 + ni * 16 + lm] = f2bf(acc[mi][ni][r]);
        }
}

// ---------------------------------------------------------------------------
// pv2/3, LDS-free: Y[k*128+i] = sum_j G2T[k][j] f[i][j].  grid (32,2,14)
// ---------------------------------------------------------------------------
__global__ __launch_bounds__(256) void pv2(
    const unsigned short* __restrict__ G2T, const unsigned short* __restrict__ F16,
    unsigned short* __restrict__ Y)
{
    const int tid = threadIdx.x;
    const int w = tid >> 6, l = tid & 63, lm = l & 15, q = l >> 4;
    const int b = blockIdx.z;
    const int k00 = blockIdx.x * 256 + w * 64;
    const int i0 = blockIdx.y * 64;
    const unsigned short* Gb = G2T + (size_t)b * CN;
    const unsigned short* Fb = F16 + (size_t)b * 16384;
    f32x4 acc[4][4] = {};
#pragma unroll
    for (int ks = 0; ks < 4; ++ks) {
        const int j0 = ks * 32 + q * 8;
        bf16x8 a[4], bb[4];
#pragma unroll
        for (int mi = 0; mi < 4; ++mi) a[mi] = *(const bf16x8*)&Gb[(size_t)(k00 + mi * 16 + lm) * 128 + j0];
#pragma unroll
        for (int ni = 0; ni < 4; ++ni) bb[ni] = *(const bf16x8*)&Fb[(i0 + ni * 16 + lm) * 128 + j0];
#pragma unroll
        for (int mi = 0; mi < 4; ++mi)
#pragma unroll
            for (int ni = 0; ni < 4; ++ni)
                acc[mi][ni] = __builtin_amdgcn_mfma_f32_16x16x32_bf16(a[mi], bb[ni], acc[mi][ni], 0, 0, 0);
    }
    unsigned short* Yb = Y + (size_t)b * CN;
#pragma unroll
    for (int mi = 0; mi < 4; ++mi)
#pragma unroll
        for (int r = 0; r < 4; ++r) {
            const int k = k00 + mi * 16 + q * 4 + r;
#pragma unroll
            for (int ni = 0; ni < 4; ++ni)
                Yb[(size_t)k * 128 + i0 + ni * 16 + lm] = f2bf(acc[mi][ni][r]);
        }
}

// ---------------------------------------------------------------------------
// y-fold (round-1, proven): Out[o][pix] += sum_t M_t[o][c] S_t[c][pix]
// grid (128, 2), block 256
// ---------------------------------------------------------------------------
__global__ __launch_bounds__(256) void fold_mfma(
    const unsigned short* __restrict__ Ap, long aPS, int aRS,
    const unsigned short* __restrict__ S, long sPS,
    float* __restrict__ Out)
{
    __shared__ unsigned short As[64][LP];
    __shared__ unsigned short Ss[128][LP];
    const int tid = threadIdx.x;
    const int p0 = blockIdx.x * 128;
    const int t0 = blockIdx.y * 7;
    const int w = tid >> 6, l = tid & 63, lm = l & 15, q = l >> 4;
    const int mo = (w & 1) * 32;
    const int no = (w >> 1) * 64;
    f32x4 acc[2][4] = {};

    for (int t = t0; t < t0 + 7; ++t) {
        __syncthreads();
#pragma unroll
        for (int i = 0; i < 2; ++i) {
            const int ch = tid + 256 * i;
            const int row = ch >> 3, c8 = (ch & 7) * 8;
            *(bf16x8*)&As[row][c8] = *(const bf16x8*)&Ap[(size_t)t * aPS + (size_t)row * aRS + c8];
        }
#pragma unroll
        for (int i = 0; i < 4; ++i) {
            const int id = tid + 256 * i;
            const int c = id & 63, p8 = (id >> 6) * 8;
            bf16x8 v = *(const bf16x8*)&S[(size_t)t * sPS + (size_t)c * NPIX + p0 + p8];
#pragma unroll
            for (int j = 0; j < 8; ++j) Ss[p8 + j][c] = (unsigned short)v[j];
        }
        __syncthreads();
#pragma unroll
        for (int ks = 0; ks < 2; ++ks) {
            const int c0 = ks * 32 + q * 8;
            bf16x8 a[2], bb[4];
#pragma unroll
            for (int mi = 0; mi < 2; ++mi) a[mi] = *(const bf16x8*)&As[mo + mi * 16 + lm][c0];
#pragma unroll
            for (int ni = 0; ni < 4; ++ni) bb[ni] = *(const bf16x8*)&Ss[no + ni * 16 + lm][c0];
#pragma unroll
            for (int mi = 0; mi < 2; ++mi)
#pragma unroll
                for (int ni = 0; ni < 4; ++ni)
                    acc[mi][ni] = __builtin_amdgcn_mfma_f32_16x16x32_bf16(a[mi], bb[ni], acc[mi][ni], 0, 0, 0);
        }
    }
#pragma unroll
    for (int mi = 0; mi < 2; ++mi)
#pragma unroll
        for (int r = 0; r < 4; ++r) {
            const int o = mo + mi * 16 + q * 4 + r;
#pragma unroll
            for (int ni = 0; ni < 4; ++ni)
                atomicAdd(&Out[(size_t)o * NPIX + p0 + no + ni * 16 + lm], acc[mi][ni][r]);
        }
}

// out = leaky(out + cb[o])
__global__ __launch_bounds__(256) void leaky_cb(float* __restrict__ O, const float* __restrict__ cb)
{
    const int i = blockIdx.x * 256 + threadIdx.x;
    float4 v = ((float4*)O)[i];
    const float b = cb[(i * 4) >> 14];
    v.x += b; v.y += b; v.z += b; v.w += b;
    v.x = v.x >= 0.f ? v.x : 0.2f * v.x;
    v.y = v.y >= 0.f ? v.y : 0.2f * v.y;
    v.z = v.z >= 0.f ? v.z : 0.2f * v.z;
    v.w = v.w >= 0.f ? v.w : 0.2f * v.w;
    ((float4*)O)[i] = v;
}

extern "C" void kernel_launch(void* const* d_in, const int* in_sizes, int n_in,
                              void* d_out, int out_size, void* d_ws, size_t ws_size,
                              hipStream_t stream)
{
    const float* x     = (const float*)d_in[0];
    const float* gc_w  = (const float*)d_in[1];
    const float* gc_b  = (const float*)d_in[2];
    const float* thc_w = (const float*)d_in[3];
    const float* thc_b = (const float*)d_in[4];
    const float* phc_w = (const float*)d_in[5];
    const float* phc_b = (const float*)d_in[6];
    const float* Wc_w  = (const float*)d_in[7];
    const float* Wc_b  = (const float*)d_in[8];
    const float* gh_w  = (const float*)d_in[9];
    const float* gh_b  = (const float*)d_in[10];
    const float* thh_w = (const float*)d_in[11];
    const float* thh_b = (const float*)d_in[12];
    const float* phh_w = (const float*)d_in[13];
    const float* phh_b = (const float*)d_in[14];
    const float* Wh_w  = (const float*)d_in[15];
    const float* Wh_b  = (const float*)d_in[16];
    const float* gw_w  = (const float*)d_in[17];
    const float* gw_b  = (const float*)d_in[18];
    const float* thw_w = (const float*)d_in[19];
    const float* thw_b = (const float*)d_in[20];
    const float* phw_w = (const float*)d_in[21];
    const float* phw_b = (const float*)d_in[22];
    const float* Ww_w  = (const float*)d_in[23];
    const float* Ww_b  = (const float*)d_in[24];
    const float* fus_w = (const float*)d_in[25];
    const float* fus_b = (const float*)d_in[26];

    float* out = (float*)d_out;

    char* p = (char*)d_ws;
    unsigned short* xT   = (unsigned short*)p; p += (size_t)BURST * CN * 2;
    unsigned short* th1  = (unsigned short*)p; p += (size_t)BURST * CN * 2;  // -> g1
    unsigned short* ph1  = (unsigned short*)p; p += (size_t)BURST * CN * 2;  // -> g2
    unsigned short* th2  = (unsigned short*)p; p += (size_t)CN * 2;
    unsigned short* ph2  = (unsigned short*)p; p += (size_t)BURST * CN * 2;  // -> g3
    unsigned short* th3  = (unsigned short*)p; p += (size_t)CN * 2;
    unsigned short* ph3  = (unsigned short*)p; p += (size_t)BURST * CN * 2;  // -> bufY
    float*          fbuf1 = (float*)p;         p += (size_t)BURST * 4096 * 4;
    float*          fbuf23 = (float*)p;        p += (size_t)2 * BURST * NPIX * 4;
    unsigned short* f16_1 = (unsigned short*)p; p += (size_t)BURST * 4096 * 2;
    unsigned short* f16_23 = (unsigned short*)p; p += (size_t)2 * BURST * NPIX * 2;
    unsigned short* w16  = (unsigned short*)p; p += (size_t)9 * 4096 * 2;
    unsigned short* M16  = (unsigned short*)p; p += (size_t)42 * 4096 * 2;
    unsigned short* Wc16 = (unsigned short*)p; p += (size_t)64 * 896 * 2;
    float*          bias9 = (float*)p;         p += (size_t)9 * 64 * 4;
    float*          cbv  = (float*)p;          p += 256;

    cast_xT<<<dim3(128, 14), 256, 0, stream>>>(x, xT);
    precompute<<<54, 256, 0, stream>>>(
        fus_w, fus_b, Wc_w, Wc_b, Wh_w, Wh_b, Ww_w, Ww_b,
        M16, Wc16, cbv,
        thc_w, phc_w, gc_w, thh_w, phh_w, gh_w, thw_w, phw_w, gw_w,
        thc_b, phc_b, gc_b, thh_b, phh_b, gh_b, thw_b, phw_b, gw_b,
        w16, bias9);
    hipMemsetAsync(fbuf1, 0, (size_t)BURST * 4096 * 4 + (size_t)2 * BURST * NPIX * 4, stream);

    fold_res<<<128, 256, 0, stream>>>(Wc16, xT, out);

    convA<<<dim3(64, 1, 58), 256, 0, stream>>>(xT, w16, bias9, th1, ph1, th2, ph2, th3, ph3);

    fgemm_nt<2, 2><<<dim3(1, 32, BURST), 256, 0, stream>>>(
        th1, NPIX, CN, ph1, NPIX, CN, fbuf1, 4096, 64, 512);
    fgemm_nt<4, 4><<<dim3(1, 32, BURST), 256, 0, stream>>>(
        th2, 8192, 0, ph2, 8192, CN, fbuf23, NPIX, 128, 256);
    fgemm_nt<4, 4><<<dim3(1, 32, BURST), 256, 0, stream>>>(
        th3, 8192, 0, ph3, 8192, CN, fbuf23 + (size_t)BURST * NPIX, NPIX, 128, 256);

    softmax64<<<BURST, 256, 0, stream>>>(fbuf1, f16_1);
    softmax128<<<2 * BURST, 256, 0, stream>>>(fbuf23, f16_23);

    convB<<<dim3(64, 1, 42), 256, 0, stream>>>(xT, w16, bias9, th1, ph1, ph2);

    pv1<<<dim3(64, 1, BURST), 256, 0, stream>>>(th1, f16_1, ph3);
    fold_mfma<<<dim3(128, 2), 256, 0, stream>>>(M16, 4096, 64, ph3, CN, out);

    pv2<<<dim3(32, 2, BURST), 256, 0, stream>>>(ph1, f16_23, ph3);
    fold_mfma<<<dim3(128, 2), 256, 0, stream>>>(M16 + (size_t)14 * 4096, 4096, 64, ph3, CN, out);

    pv2<<<dim3(32, 2, BURST), 256, 0, stream>>>(ph2, f16_23 + (size_t)BURST * NPIX, ph3);
    fold_mfma<<<dim3(128, 2), 256, 0, stream>>>(M16 + (size_t)28 * 4096, 4096, 64, ph3, CN, out);

    leaky_cb<<<1024, 256, 0, stream>>>(out, cbv);
}

// Round 4
// 484.188 us; speedup vs baseline: 3.4506x; 1.1934x over previous
//
#include <hip/hip_runtime.h>

#define NF 64
#define BURST 14
#define NPIX 16384
#define CN (NF * NPIX)
#define LP 72

typedef short bf16x8 __attribute__((ext_vector_type(8)));
typedef float f32x4 __attribute__((ext_vector_type(4)));
typedef unsigned short us4 __attribute__((ext_vector_type(4)));

__device__ inline unsigned short f2bf(float f) {
    unsigned int u = __float_as_uint(f);
    return (unsigned short)((u + 0x7fffu + ((u >> 16) & 1u)) >> 16);
}
__device__ inline float bf2f(unsigned short u) {
    return __uint_as_float(((unsigned int)u) << 16);
}

// ---------------------------------------------------------------------------
// x fp32 [b][c][pix] -> xb bf16 same layout + xT bf16 [b][pix][c] + half sums
// S[b][dlt][c] = sum_{k<8192} x[c][dlt*8192+k]  (atomic fp32, pre-zeroed)
// grid (128, 14), block 256
// ---------------------------------------------------------------------------
__global__ __launch_bounds__(256) void cast_x(const float* __restrict__ X,
                                              unsigned short* __restrict__ XB,
                                              unsigned short* __restrict__ XT,
                                              float* __restrict__ S)
{
    __shared__ unsigned short Xs[128][LP];
    const int tid = threadIdx.x;
    const int p0 = blockIdx.x * 128;
    const int b = blockIdx.y;
    const size_t boff = (size_t)b * CN;
#pragma unroll
    for (int i = 0; i < 8; ++i) {
        const int id = tid + 256 * i;
        const int c = id >> 5, p4 = (id & 31) * 4;
        float4 v = *(const float4*)&X[boff + (size_t)c * NPIX + p0 + p4];
        us4 r;
        r.x = f2bf(v.x); r.y = f2bf(v.y); r.z = f2bf(v.z); r.w = f2bf(v.w);
        *(us4*)&XB[boff + (size_t)c * NPIX + p0 + p4] = r;
        Xs[p4 + 0][c] = r.x; Xs[p4 + 1][c] = r.y;
        Xs[p4 + 2][c] = r.z; Xs[p4 + 3][c] = r.w;
    }
    __syncthreads();
#pragma unroll
    for (int i = 0; i < 4; ++i) {
        const int id = tid + 256 * i;
        const int row = id >> 3, c8 = (id & 7) * 8;
        *(bf16x8*)&XT[boff + (size_t)(p0 + row) * 64 + c8] = *(const bf16x8*)&Xs[row][c8];
    }
    if (tid < 64) {
        float sv = 0.f;
        for (int pp = 0; pp < 128; ++pp) sv += bf2f(Xs[pp][tid]);
        atomicAdd(&S[(b * 2 + (p0 >= 8192 ? 1 : 0)) * 64 + tid], sv);
    }
}

// ---------------------------------------------------------------------------
// Precompute, every block fully parallel:
//  blocks 0..41  : M16[g][b] = bf16(Fsub @ Wg)
//  blocks 42..97 : Wc16 (1024 elements each)
//  blocks 98..105: cb (8 o-rows each, lane-parallel over ch)
// ---------------------------------------------------------------------------
__global__ __launch_bounds__(256) void precompute(
    const float* __restrict__ fus_w, const float* __restrict__ fus_b,
    const float* __restrict__ Wc, const float* __restrict__ bWc,
    const float* __restrict__ Wh, const float* __restrict__ bWh,
    const float* __restrict__ Ww, const float* __restrict__ bWw,
    unsigned short* __restrict__ M16, unsigned short* __restrict__ Wc16,
    float* __restrict__ cb)
{
    const int blk = blockIdx.x, tid = threadIdx.x;
    if (blk < 42) {
        __shared__ float Fl[64][65];
        __shared__ float Wl[64][65];
        const int g = blk / 14, b = blk % 14;
        const float* Wg = (g == 0) ? Wc : (g == 1) ? Wh : Ww;
#pragma unroll
        for (int i = 0; i < 4; ++i) {
            const int id = tid + 256 * i;
            const int r = id >> 4, c4 = (id & 15) * 4;
            float4 v = *(const float4*)&fus_w[r * 2688 + g * 896 + b * 64 + c4];
            Fl[r][c4] = v.x; Fl[r][c4 + 1] = v.y; Fl[r][c4 + 2] = v.z; Fl[r][c4 + 3] = v.w;
            float4 u = *(const float4*)&Wg[r * 64 + c4];
            Wl[r][c4] = u.x; Wl[r][c4 + 1] = u.y; Wl[r][c4 + 2] = u.z; Wl[r][c4 + 3] = u.w;
        }
        __syncthreads();
        const int o = tid & 63, qq = tid >> 6;
        float s[16];
#pragma unroll
        for (int i = 0; i < 16; ++i) s[i] = 0.f;
        for (int c2 = 0; c2 < 64; ++c2) {
            const float fv = Fl[o][c2];
#pragma unroll
            for (int i = 0; i < 16; ++i) s[i] += fv * Wl[c2][qq * 16 + i];
        }
        unsigned short* Mout = M16 + (size_t)blk * 4096;
#pragma unroll
        for (int i = 0; i < 16; i += 4) {
            us4 r4; r4.x = f2bf(s[i]); r4.y = f2bf(s[i + 1]); r4.z = f2bf(s[i + 2]); r4.w = f2bf(s[i + 3]);
            *(us4*)&Mout[o * 64 + qq * 16 + i] = r4;
        }
    } else if (blk < 98) {
        const int e0 = (blk - 42) * 1024 + tid * 4;
        const int o = e0 / 896, bc = e0 - o * 896;
        float4 a = *(const float4*)&fus_w[o * 2688 + bc];
        float4 b2 = *(const float4*)&fus_w[o * 2688 + 896 + bc];
        float4 c3 = *(const float4*)&fus_w[o * 2688 + 1792 + bc];
        us4 r;
        r.x = f2bf(a.x + b2.x + c3.x); r.y = f2bf(a.y + b2.y + c3.y);
        r.z = f2bf(a.z + b2.z + c3.z); r.w = f2bf(a.w + b2.w + c3.w);
        *(us4*)&Wc16[e0] = r;
    } else {
        __shared__ float red[256];
        const int o = (blk - 98) * 8 + (tid >> 5);
        const int lane = tid & 31;
        float s = 0.f;
        for (int t = 0; t < 84; ++t) {
            const int ch = lane + 32 * t;
            const int g = ch / 896, c2 = ch & 63;
            const float bg = (g == 0) ? bWc[c2] : (g == 1) ? bWh[c2] : bWw[c2];
            s += fus_w[o * 2688 + ch] * bg;
        }
        red[tid] = s;
        __syncthreads();
        if (tid < 8) {
            const int oo = (blk - 98) * 8 + tid;
            float t = fus_b[oo];
            for (int i = 0; i < 32; ++i) t += red[tid * 32 + i];
            cb[oo] = t;
        }
    }
}

// ---------------------------------------------------------------------------
// Gram kernel: G[b][z][c][c'] (fp32 atomics, pre-zeroed)
//  z=0: self-Gram over K=16384 (chunk 2048)
//  z=1..4: cross-Gram x0(dlt-half) x xb(dlt'-half), K=8192 (chunk 1024)
// grid (8, 14, 5), block 256
// ---------------------------------------------------------------------------
__global__ __launch_bounds__(256) void gram(
    const unsigned short* __restrict__ XB, float* __restrict__ G)
{
    const int tid = threadIdx.x;
    const int w = tid >> 6, l = tid & 63, lm = l & 15, q = l >> 4;
    const int b = blockIdx.y, z = blockIdx.z;
    const unsigned short* A;
    const unsigned short* B;
    int k0, ksteps;
    if (z == 0) {
        A = XB + (size_t)b * CN; B = A;
        k0 = blockIdx.x * 2048; ksteps = 64;
    } else {
        const int dl = (z - 1) >> 1, dp = (z - 1) & 1;
        A = XB + (size_t)dl * 8192;                      // batch 0, dl half
        B = XB + (size_t)b * CN + (size_t)dp * 8192;     // batch b, dp half
        k0 = blockIdx.x * 1024; ksteps = 32;
    }
    const int mo = (w & 1) * 32, no = (w >> 1) * 32;
    f32x4 acc[2][2] = {};
    for (int ks = 0; ks < ksteps; ++ks) {
        const int k = k0 + ks * 32 + q * 8;
        bf16x8 a[2], bb[2];
#pragma unroll
        for (int mi = 0; mi < 2; ++mi) a[mi] = *(const bf16x8*)&A[(size_t)(mo + mi * 16 + lm) * NPIX + k];
#pragma unroll
        for (int ni = 0; ni < 2; ++ni) bb[ni] = *(const bf16x8*)&B[(size_t)(no + ni * 16 + lm) * NPIX + k];
#pragma unroll
        for (int mi = 0; mi < 2; ++mi)
#pragma unroll
            for (int ni = 0; ni < 2; ++ni)
                acc[mi][ni] = __builtin_amdgcn_mfma_f32_16x16x32_bf16(a[mi], bb[ni], acc[mi][ni], 0, 0, 0);
    }
    float* Gp = G + (size_t)(b * 5 + z) * 4096;
#pragma unroll
    for (int mi = 0; mi < 2; ++mi)
#pragma unroll
        for (int r = 0; r < 4; ++r)
#pragma unroll
            for (int ni = 0; ni < 2; ++ni)
                atomicAdd(&Gp[(mo + mi * 16 + q * 4 + r) * 64 + no + ni * 16 + lm], acc[mi][ni][r]);
}

// ---------------------------------------------------------------------------
// Sandwich: logits from Grams (fp32).
//  y=0: part1: f1[c][d] = (Wth G0 Wph^T)[c][d] + u[c]bph[d] + bth[c]v[d] + 16384 bth bph
//  y=1..4: part2 (dl,dp)  ->  f2[2t+dl][2t'+dp] (K=8192 bias)
//  y=5..8: part3 likewise
// grid (14, 9), block 256
// ---------------------------------------------------------------------------
__global__ __launch_bounds__(256) void sandwich(
    const float* __restrict__ thc_w, const float* __restrict__ phc_w,
    const float* __restrict__ thc_b, const float* __restrict__ phc_b,
    const float* __restrict__ thh_w, const float* __restrict__ phh_w,
    const float* __restrict__ thh_b, const float* __restrict__ phh_b,
    const float* __restrict__ thw_w, const float* __restrict__ phw_w,
    const float* __restrict__ thw_b, const float* __restrict__ phw_b,
    const float* __restrict__ G, const float* __restrict__ S,
    float* __restrict__ f1, float* __restrict__ f2)
{
    __shared__ float Wt[64][65], Wp[64][65], Gl[64][65], Tl[64][65];
    __shared__ float sth[64], sph[64], uu[64], vv[64], btl[64], bpl[64];
    const int b = blockIdx.x, y = blockIdx.y, tid = threadIdx.x;
    const float *Wth_g, *Wph_g, *bth_g, *bph_g, *Gp;
    float* outp; int dl = 0, dp = 0; float Kn;
    if (y == 0) {
        Wth_g = thc_w; Wph_g = phc_w; bth_g = thc_b; bph_g = phc_b;
        Gp = G + (size_t)(b * 5) * 4096; Kn = 16384.f;
        outp = f1 + (size_t)b * 4096;
    } else {
        const int part = (y - 1) / 4, e = (y - 1) & 3;
        dl = e >> 1; dp = e & 1;
        if (part == 0) { Wth_g = thh_w; Wph_g = phh_w; bth_g = thh_b; bph_g = phh_b; }
        else           { Wth_g = thw_w; Wph_g = phw_w; bth_g = thw_b; bph_g = phw_b; }
        Gp = G + (size_t)(b * 5 + 1 + e) * 4096; Kn = 8192.f;
        outp = f2 + (size_t)(part * 14 + b) * 16384;
    }
#pragma unroll
    for (int i = 0; i < 4; ++i) {
        const int id = tid + 256 * i;
        const int r = id >> 4, c4 = (id & 15) * 4;
        float4 v = *(const float4*)&Wth_g[r * 64 + c4];
        Wt[r][c4] = v.x; Wt[r][c4 + 1] = v.y; Wt[r][c4 + 2] = v.z; Wt[r][c4 + 3] = v.w;
        float4 u = *(const float4*)&Wph_g[r * 64 + c4];
        Wp[r][c4] = u.x; Wp[r][c4 + 1] = u.y; Wp[r][c4 + 2] = u.z; Wp[r][c4 + 3] = u.w;
        float4 g = *(const float4*)&Gp[r * 64 + c4];
        Gl[r][c4] = g.x; Gl[r][c4 + 1] = g.y; Gl[r][c4 + 2] = g.z; Gl[r][c4 + 3] = g.w;
    }
    if (tid < 64) {
        if (y == 0) { const float sf = S[b * 128 + tid] + S[b * 128 + 64 + tid]; sth[tid] = sf; sph[tid] = sf; }
        else { sth[tid] = S[dl * 64 + tid]; sph[tid] = S[b * 128 + dp * 64 + tid]; }
        btl[tid] = bth_g[tid]; bpl[tid] = bph_g[tid];
    }
    __syncthreads();
    if (tid < 64) {
        float su = 0.f, sv = 0.f;
        for (int c = 0; c < 64; ++c) { su += Wt[tid][c] * sth[c]; sv += Wp[tid][c] * sph[c]; }
        uu[tid] = su; vv[tid] = sv;
    }
    const int t = tid & 63, qq = tid >> 6;
    float r16[16];
#pragma unroll
    for (int i = 0; i < 16; ++i) r16[i] = 0.f;
    for (int c = 0; c < 64; ++c) {
        const float fv = Wt[t][c];
#pragma unroll
        for (int i = 0; i < 16; ++i) r16[i] += fv * Gl[c][qq * 16 + i];
    }
#pragma unroll
    for (int i = 0; i < 16; ++i) Tl[t][qq * 16 + i] = r16[i];
    __syncthreads();
#pragma unroll
    for (int i = 0; i < 16; ++i) r16[i] = 0.f;
    for (int c = 0; c < 64; ++c) {
        const float tv = Tl[t][c];
#pragma unroll
        for (int i = 0; i < 16; ++i) r16[i] += tv * Wp[qq * 16 + i][c];
    }
    if (y == 0) {
#pragma unroll
        for (int i = 0; i < 16; ++i) {
            const int d = qq * 16 + i;
            outp[t * 64 + d] = r16[i] + uu[t] * bpl[d] + btl[t] * vv[d] + Kn * btl[t] * bpl[d];
        }
    } else {
#pragma unroll
        for (int i = 0; i < 16; ++i) {
            const int tp = qq * 16 + i;
            outp[(2 * t + dl) * 128 + 2 * tp + dp] =
                r16[i] + uu[t] * bpl[tp] + btl[t] * vv[tp] + Kn * btl[t] * bpl[tp];
        }
    }
}

// ---------------------------------------------------------------------------
// Merged softmax: blocks 0..13 -> part1 (64x64, over c for fixed d)
//                 blocks 14..41 -> parts 2/3 (128x128, over i for fixed j)
// ---------------------------------------------------------------------------
__global__ __launch_bounds__(256) void softmax_all(
    const float* __restrict__ f1, const float* __restrict__ f2,
    unsigned short* __restrict__ o1, unsigned short* __restrict__ o23)
{
    __shared__ float red[256];
    __shared__ float mxA[128], invA[128];
    const int bx = blockIdx.x, tid = threadIdx.x;
    if (bx < 14) {
        const float* Fb = f1 + (size_t)bx * 4096;
        unsigned short* Ob = o1 + (size_t)bx * 4096;
        const int d = tid & 63, qq = tid >> 6;
        float mx = -1e30f;
        for (int c = qq * 16; c < qq * 16 + 16; ++c) mx = fmaxf(mx, Fb[c * 64 + d]);
        red[tid] = mx;
        __syncthreads();
        if (tid < 64) mxA[tid] = fmaxf(fmaxf(red[tid], red[64 + tid]), fmaxf(red[128 + tid], red[192 + tid]));
        __syncthreads();
        const float m = mxA[d];
        float s = 0.f;
        for (int c = qq * 16; c < qq * 16 + 16; ++c) s += __expf(Fb[c * 64 + d] - m);
        red[tid] = s;
        __syncthreads();
        if (tid < 64) invA[tid] = 1.f / (red[tid] + red[64 + tid] + red[128 + tid] + red[192 + tid]);
        __syncthreads();
        const int e0 = tid * 16;
#pragma unroll
        for (int i = 0; i < 16; i += 4) {
            us4 r4;
            const int dd = (e0 & 63) + i;
            r4.x = f2bf(__expf(Fb[e0 + i] - mxA[dd]) * invA[dd]);
            r4.y = f2bf(__expf(Fb[e0 + i + 1] - mxA[dd + 1]) * invA[dd + 1]);
            r4.z = f2bf(__expf(Fb[e0 + i + 2] - mxA[dd + 2]) * invA[dd + 2]);
            r4.w = f2bf(__expf(Fb[e0 + i + 3] - mxA[dd + 3]) * invA[dd + 3]);
            *(us4*)&Ob[e0 + i] = r4;
        }
    } else {
        const int idx = bx - 14;
        const float* Fb = f2 + (size_t)idx * 16384;
        unsigned short* Ob = o23 + (size_t)idx * 16384;
        const int j = tid & 127, ih = tid >> 7;
        float mx = -1e30f;
        for (int i = ih * 64; i < ih * 64 + 64; ++i) mx = fmaxf(mx, Fb[i * 128 + j]);
        red[tid] = mx;
        __syncthreads();
        if (tid < 128) mxA[tid] = fmaxf(red[tid], red[128 + tid]);
        __syncthreads();
        const float m = mxA[j];
        float s = 0.f;
        for (int i = ih * 64; i < ih * 64 + 64; ++i) s += __expf(Fb[i * 128 + j] - m);
        red[tid] = s;
        __syncthreads();
        if (tid < 128) invA[tid] = 1.f / (red[tid] + red[128 + tid]);
        __syncthreads();
        const int e0 = tid * 64;
        for (int i = 0; i < 64; i += 4) {
            us4 r4;
            const int jj = (e0 & 127) + i;
            r4.x = f2bf(__expf(Fb[e0 + i] - mxA[jj]) * invA[jj]);
            r4.y = f2bf(__expf(Fb[e0 + i + 1] - mxA[jj + 1]) * invA[jj + 1]);
            r4.z = f2bf(__expf(Fb[e0 + i + 2] - mxA[jj + 2]) * invA[jj + 2]);
            r4.w = f2bf(__expf(Fb[e0 + i + 3] - mxA[jj + 3]) * invA[jj + 3]);
            *(us4*)&Ob[e0 + i] = r4;
        }
    }
}

// ---------------------------------------------------------------------------
// K-matrices (fold g-conv through softmaxed f):
//  y=0: K1[c][c'] = sum_d f1[c][d] Wg[d][c'];  B1[c] = sum_d f1[c][d] bg[d]
//  y=1/2: K2[part][b][dlt][i][c] = sum_t f2[i][2t+dlt] Wg[t][c];
//         B2[i] = sum_t (f2[i][2t]+f2[i][2t+1]) bg[t]
// grid (14, 3), block 256
// ---------------------------------------------------------------------------
__global__ __launch_bounds__(256) void kmat(
    const unsigned short* __restrict__ f16_1, const unsigned short* __restrict__ f16_23,
    const float* __restrict__ gcw, const float* __restrict__ gcb,
    const float* __restrict__ ghw, const float* __restrict__ ghb,
    const float* __restrict__ gww, const float* __restrict__ gwb,
    unsigned short* __restrict__ K1, float* __restrict__ B1,
    unsigned short* __restrict__ K2, float* __restrict__ B2)
{
    __shared__ float fl[128][129];
    __shared__ float Wg[64][65];
    __shared__ float bgl[64];
    const int b = blockIdx.x, y = blockIdx.y, tid = threadIdx.x;
    if (y == 0) {
        const unsigned short* fp = f16_1 + (size_t)b * 4096;
#pragma unroll
        for (int i = 0; i < 16; ++i) {
            const int id = tid + 256 * i;
            fl[id >> 6][id & 63] = bf2f(fp[id]);
        }
#pragma unroll
        for (int i = 0; i < 16; ++i) {
            const int id = tid + 256 * i;
            Wg[id >> 6][id & 63] = gcw[id];
        }
        if (tid < 64) bgl[tid] = gcb[tid];
        __syncthreads();
        const int c = tid & 63, qq = tid >> 6;
        float r16[16];
#pragma unroll
        for (int i = 0; i < 16; ++i) r16[i] = 0.f;
        for (int d = 0; d < 64; ++d) {
            const float fv = fl[c][d];
#pragma unroll
            for (int i = 0; i < 16; ++i) r16[i] += fv * Wg[d][qq * 16 + i];
        }
        unsigned short* Kp = K1 + (size_t)b * 4096;
#pragma unroll
        for (int i = 0; i < 16; i += 4) {
            us4 r4; r4.x = f2bf(r16[i]); r4.y = f2bf(r16[i + 1]); r4.z = f2bf(r16[i + 2]); r4.w = f2bf(r16[i + 3]);
            *(us4*)&Kp[c * 64 + qq * 16 + i] = r4;
        }
        if (tid < 64) {
            float s = 0.f;
            for (int d = 0; d < 64; ++d) s += fl[tid][d] * bgl[d];
            B1[b * 64 + tid] = s;
        }
    } else {
        const int part = y - 1;
        const unsigned short* fp = f16_23 + (size_t)(part * 14 + b) * 16384;
        const float* wg = part ? gww : ghw;
        const float* bg = part ? gwb : ghb;
#pragma unroll
        for (int i = 0; i < 64; ++i) {
            const int id = tid + 256 * i;
            fl[id >> 7][id & 127] = bf2f(fp[id]);
        }
#pragma unroll
        for (int i = 0; i < 16; ++i) {
            const int id = tid + 256 * i;
            Wg[id >> 6][id & 63] = wg[id];
        }
        if (tid < 64) bgl[tid] = bg[tid];
        __syncthreads();
        const int i = tid & 127, half = tid >> 7;
        unsigned short* Kp = K2 + (size_t)(part * 14 + b) * 16384;
        for (int dlt = 0; dlt < 2; ++dlt) {
            for (int cc = 0; cc < 32; cc += 4) {
                const int c = half * 32 + cc;
                float a0 = 0.f, a1 = 0.f, a2 = 0.f, a3 = 0.f;
                for (int t = 0; t < 64; ++t) {
                    const float fv = fl[i][2 * t + dlt];
                    a0 += fv * Wg[t][c]; a1 += fv * Wg[t][c + 1];
                    a2 += fv * Wg[t][c + 2]; a3 += fv * Wg[t][c + 3];
                }
                us4 r4; r4.x = f2bf(a0); r4.y = f2bf(a1); r4.z = f2bf(a2); r4.w = f2bf(a3);
                *(us4*)&Kp[dlt * 8192 + i * 64 + c] = r4;
            }
        }
        if (tid < 128) {
            float s = 0.f;
            for (int t = 0; t < 64; ++t) s += (fl[tid][2 * t] + fl[tid][2 * t + 1]) * bgl[t];
            B2[(part * 14 + b) * 128 + tid] = s;
        }
    }
}

// ---------------------------------------------------------------------------
// Residual fold, LDS-free: Out[o][pix] = sum_{b,c} Wc16[o][b*64+c] xT[b][pix][c]
// grid (256), block 256.  Plain stores (first writer of out).
// ---------------------------------------------------------------------------
__global__ __launch_bounds__(256) void fold_res(
    const unsigned short* __restrict__ Wcomb, const unsigned short* __restrict__ XT,
    float* __restrict__ Out)
{
    const int tid = threadIdx.x;
    const int w = tid >> 6, l = tid & 63, lm = l & 15, q = l >> 4;
    const int p0 = blockIdx.x * 64 + (w >> 1) * 32;
    const int oh = (w & 1) * 32;
    f32x4 acc[2][2] = {};
    for (int b = 0; b < 14; ++b) {
#pragma unroll
        for (int ks = 0; ks < 2; ++ks) {
            const int c0 = ks * 32 + q * 8;
            bf16x8 a[2], bb[2];
#pragma unroll
            for (int mi = 0; mi < 2; ++mi)
                a[mi] = *(const bf16x8*)&Wcomb[(oh + mi * 16 + lm) * 896 + b * 64 + c0];
#pragma unroll
            for (int ni = 0; ni < 2; ++ni)
                bb[ni] = *(const bf16x8*)&XT[(size_t)b * CN + (size_t)(p0 + ni * 16 + lm) * 64 + c0];
#pragma unroll
            for (int mi = 0; mi < 2; ++mi)
#pragma unroll
                for (int ni = 0; ni < 2; ++ni)
                    acc[mi][ni] = __builtin_amdgcn_mfma_f32_16x16x32_bf16(a[mi], bb[ni], acc[mi][ni], 0, 0, 0);
        }
    }
#pragma unroll
    for (int mi = 0; mi < 2; ++mi)
#pragma unroll
        for (int r = 0; r < 4; ++r) {
            const int o = oh + mi * 16 + q * 4 + r;
#pragma unroll
            for (int ni = 0; ni < 2; ++ni)
                Out[(size_t)o * NPIX + p0 + ni * 16 + lm] = acc[mi][ni][r];
        }
}

// ---------------------------------------------------------------------------
// pv1: Y[p*64+c] = sum_{c'} xT[p][c'] K1[c][c'] + B1[c].  grid (64,1,14)
// ---------------------------------------------------------------------------
__global__ __launch_bounds__(256) void pv1k(
    const unsigned short* __restrict__ XT, const unsigned short* __restrict__ K1,
    const float* __restrict__ B1, unsigned short* __restrict__ Y)
{
    const int tid = threadIdx.x;
    const int w = tid >> 6, l = tid & 63, lm = l & 15, q = l >> 4;
    const int b = blockIdx.z;
    const int p0 = blockIdx.x * 256 + w * 64;
    const unsigned short* Xb = XT + (size_t)b * CN;
    const unsigned short* Kb = K1 + (size_t)b * 4096;
    f32x4 acc[4][4] = {};
#pragma unroll
    for (int ks = 0; ks < 2; ++ks) {
        const int c0 = ks * 32 + q * 8;
        bf16x8 a[4], bb[4];
#pragma unroll
        for (int mi = 0; mi < 4; ++mi) a[mi] = *(const bf16x8*)&Xb[(size_t)(p0 + mi * 16 + lm) * 64 + c0];
#pragma unroll
        for (int ni = 0; ni < 4; ++ni) bb[ni] = *(const bf16x8*)&Kb[(ni * 16 + lm) * 64 + c0];
#pragma unroll
        for (int mi = 0; mi < 4; ++mi)
#pragma unroll
            for (int ni = 0; ni < 4; ++ni)
                acc[mi][ni] = __builtin_amdgcn_mfma_f32_16x16x32_bf16(a[mi], bb[ni], acc[mi][ni], 0, 0, 0);
    }
    unsigned short* Yb = Y + (size_t)b * CN;
#pragma unroll
    for (int mi = 0; mi < 4; ++mi)
#pragma unroll
        for (int r = 0; r < 4; ++r) {
            const int p = p0 + mi * 16 + q * 4 + r;
#pragma unroll
            for (int ni = 0; ni < 4; ++ni) {
                const int c = ni * 16 + lm;
                Yb[(size_t)p * 64 + c] = f2bf(acc[mi][ni][r] + B1[b * 64 + c]);
            }
        }
}

// ---------------------------------------------------------------------------
// pv2/3: Y[k*128+i] = sum_dlt sum_c xT[dlt*8192+k][c] K2[dlt][i][c] + B2[i]
// grid (32, 2, 28): z -> part (z/14), b (z%14)
// ---------------------------------------------------------------------------
__global__ __launch_bounds__(256) void pv23k(
    const unsigned short* __restrict__ XT, const unsigned short* __restrict__ K2,
    const float* __restrict__ B2, unsigned short* __restrict__ Y2,
    unsigned short* __restrict__ Y3)
{
    const int tid = threadIdx.x;
    const int w = tid >> 6, l = tid & 63, lm = l & 15, q = l >> 4;
    const int part = blockIdx.z / 14, b = blockIdx.z % 14;
    const int k00 = blockIdx.x * 256 + w * 64;
    const int i0 = blockIdx.y * 64;
    const unsigned short* Xb = XT + (size_t)b * CN;
    const unsigned short* Kb = K2 + (size_t)(part * 14 + b) * 16384;
    const float* Bb = B2 + (part * 14 + b) * 128;
    f32x4 acc[4][4] = {};
#pragma unroll
    for (int dlt = 0; dlt < 2; ++dlt) {
#pragma unroll
        for (int ks = 0; ks < 2; ++ks) {
            const int c0 = ks * 32 + q * 8;
            bf16x8 a[4], bb[4];
#pragma unroll
            for (int mi = 0; mi < 4; ++mi)
                a[mi] = *(const bf16x8*)&Xb[(size_t)(dlt * 8192 + k00 + mi * 16 + lm) * 64 + c0];
#pragma unroll
            for (int ni = 0; ni < 4; ++ni)
                bb[ni] = *(const bf16x8*)&Kb[dlt * 8192 + (i0 + ni * 16 + lm) * 64 + c0];
#pragma unroll
            for (int mi = 0; mi < 4; ++mi)
#pragma unroll
                for (int ni = 0; ni < 4; ++ni)
                    acc[mi][ni] = __builtin_amdgcn_mfma_f32_16x16x32_bf16(a[mi], bb[ni], acc[mi][ni], 0, 0, 0);
        }
    }
    unsigned short* Yb = (part ? Y3 : Y2) + (size_t)b * CN;
#pragma unroll
    for (int mi = 0; mi < 4; ++mi)
#pragma unroll
        for (int r = 0; r < 4; ++r) {
            const int k = k00 + mi * 16 + q * 4 + r;
#pragma unroll
            for (int ni = 0; ni < 4; ++ni) {
                const int ii = i0 + ni * 16 + lm;
                Yb[(size_t)k * 128 + ii] = f2bf(acc[mi][ni][r] + Bb[ii]);
            }
        }
}

// ---------------------------------------------------------------------------
// Merged y-fold: Out[o][pix] += sum_t M[z][t][o][c2] y_z[t][c2][pix]
// grid (128, 2, 3), block 256
// ---------------------------------------------------------------------------
__global__ __launch_bounds__(256) void yfold(
    const unsigned short* __restrict__ M16,
    const unsigned short* __restrict__ Y1, const unsigned short* __restrict__ Y2,
    const unsigned short* __restrict__ Y3, float* __restrict__ Out)
{
    __shared__ unsigned short As[64][LP];
    __shared__ unsigned short Ss[128][LP];
    const int tid = threadIdx.x;
    const int z = blockIdx.z;
    const unsigned short* Ap = M16 + (size_t)z * 14 * 4096;
    const unsigned short* S = (z == 0) ? Y1 : (z == 1) ? Y2 : Y3;
    const int p0 = blockIdx.x * 128;
    const int t0 = blockIdx.y * 7;
    const int w = tid >> 6, l = tid & 63, lm = l & 15, q = l >> 4;
    const int mo = (w & 1) * 32;
    const int no = (w >> 1) * 64;
    f32x4 acc[2][4] = {};

    for (int t = t0; t < t0 + 7; ++t) {
        __syncthreads();
#pragma unroll
        for (int i = 0; i < 2; ++i) {
            const int ch = tid + 256 * i;
            const int row = ch >> 3, c8 = (ch & 7) * 8;
            *(bf16x8*)&As[row][c8] = *(const bf16x8*)&Ap[(size_t)t * 4096 + (size_t)row * 64 + c8];
        }
#pragma unroll
        for (int i = 0; i < 4; ++i) {
            const int id = tid + 256 * i;
            const int c = id & 63, p8 = (id >> 6) * 8;
            bf16x8 v = *(const bf16x8*)&S[(size_t)t * CN + (size_t)c * NPIX + p0 + p8];
#pragma unroll
            for (int j = 0; j < 8; ++j) Ss[p8 + j][c] = (unsigned short)v[j];
        }
        __syncthreads();
#pragma unroll
        for (int ks = 0; ks < 2; ++ks) {
            const int c0 = ks * 32 + q * 8;
            bf16x8 a[2], bb[4];
#pragma unroll
            for (int mi = 0; mi < 2; ++mi) a[mi] = *(const bf16x8*)&As[mo + mi * 16 + lm][c0];
#pragma unroll
            for (int ni = 0; ni < 4; ++ni) bb[ni] = *(const bf16x8*)&Ss[no + ni * 16 + lm][c0];
#pragma unroll
            for (int mi = 0; mi < 2; ++mi)
#pragma unroll
                for (int ni = 0; ni < 4; ++ni)
                    acc[mi][ni] = __builtin_amdgcn_mfma_f32_16x16x32_bf16(a[mi], bb[ni], acc[mi][ni], 0, 0, 0);
        }
    }
#pragma unroll
    for (int mi = 0; mi < 2; ++mi)
#pragma unroll
        for (int r = 0; r < 4; ++r) {
            const int o = mo + mi * 16 + q * 4 + r;
#pragma unroll
            for (int ni = 0; ni < 4; ++ni)
                atomicAdd(&Out[(size_t)o * NPIX + p0 + no + ni * 16 + lm], acc[mi][ni][r]);
        }
}

// out = leaky(out + cb[o])
__global__ __launch_bounds__(256) void leaky_cb(float* __restrict__ O, const float* __restrict__ cb)
{
    const int i = blockIdx.x * 256 + threadIdx.x;
    float4 v = ((float4*)O)[i];
    const float b = cb[(i * 4) >> 14];
    v.x += b; v.y += b; v.z += b; v.w += b;
    v.x = v.x >= 0.f ? v.x : 0.2f * v.x;
    v.y = v.y >= 0.f ? v.y : 0.2f * v.y;
    v.z = v.z >= 0.f ? v.z : 0.2f * v.z;
    v.w = v.w >= 0.f ? v.w : 0.2f * v.w;
    ((float4*)O)[i] = v;
}

extern "C" void kernel_launch(void* const* d_in, const int* in_sizes, int n_in,
                              void* d_out, int out_size, void* d_ws, size_t ws_size,
                              hipStream_t stream)
{
    const float* x     = (const float*)d_in[0];
    const float* gc_w  = (const float*)d_in[1];
    const float* gc_b  = (const float*)d_in[2];
    const float* thc_w = (const float*)d_in[3];
    const float* thc_b = (const float*)d_in[4];
    const float* phc_w = (const float*)d_in[5];
    const float* phc_b = (const float*)d_in[6];
    const float* Wc_w  = (const float*)d_in[7];
    const float* Wc_b  = (const float*)d_in[8];
    const float* gh_w  = (const float*)d_in[9];
    const float* gh_b  = (const float*)d_in[10];
    const float* thh_w = (const float*)d_in[11];
    const float* thh_b = (const float*)d_in[12];
    const float* phh_w = (const float*)d_in[13];
    const float* phh_b = (const float*)d_in[14];
    const float* Wh_w  = (const float*)d_in[15];
    const float* Wh_b  = (const float*)d_in[16];
    const float* gw_w  = (const float*)d_in[17];
    const float* gw_b  = (const float*)d_in[18];
    const float* thw_w = (const float*)d_in[19];
    const float* thw_b = (const float*)d_in[20];
    const float* phw_w = (const float*)d_in[21];
    const float* phw_b = (const float*)d_in[22];
    const float* Ww_w  = (const float*)d_in[23];
    const float* Ww_b  = (const float*)d_in[24];
    const float* fus_w = (const float*)d_in[25];
    const float* fus_b = (const float*)d_in[26];

    float* out = (float*)d_out;

    char* p = (char*)d_ws;
    unsigned short* xb   = (unsigned short*)p; p += (size_t)BURST * CN * 2;
    unsigned short* xT   = (unsigned short*)p; p += (size_t)BURST * CN * 2;
    unsigned short* y1   = (unsigned short*)p; p += (size_t)BURST * CN * 2;
    unsigned short* y2   = (unsigned short*)p; p += (size_t)BURST * CN * 2;
    unsigned short* y3   = (unsigned short*)p; p += (size_t)BURST * CN * 2;
    float*          Gbuf = (float*)p;          p += (size_t)BURST * 5 * 4096 * 4;
    float*          sbuf = (float*)p;          p += (size_t)BURST * 2 * 64 * 4;
    float*          f1b  = (float*)p;          p += (size_t)BURST * 4096 * 4;
    float*          f2b  = (float*)p;          p += (size_t)2 * BURST * 16384 * 4;
    unsigned short* f16_1 = (unsigned short*)p; p += (size_t)BURST * 4096 * 2;
    unsigned short* f16_23 = (unsigned short*)p; p += (size_t)2 * BURST * 16384 * 2;
    unsigned short* K1   = (unsigned short*)p; p += (size_t)BURST * 4096 * 2;
    unsigned short* K2   = (unsigned short*)p; p += (size_t)2 * BURST * 16384 * 2;
    float*          B1   = (float*)p;          p += (size_t)BURST * 64 * 4;
    float*          B2   = (float*)p;          p += (size_t)2 * BURST * 128 * 4;
    unsigned short* M16  = (unsigned short*)p; p += (size_t)42 * 4096 * 2;
    unsigned short* Wc16 = (unsigned short*)p; p += (size_t)64 * 896 * 2;
    float*          cbv  = (float*)p;          p += 256;

    // zero G + s (contiguous)
    hipMemsetAsync(Gbuf, 0, ((size_t)BURST * 5 * 4096 + (size_t)BURST * 2 * 64) * 4, stream);

    cast_x<<<dim3(128, 14), 256, 0, stream>>>(x, xb, xT, sbuf);
    precompute<<<106, 256, 0, stream>>>(fus_w, fus_b, Wc_w, Wc_b, Wh_w, Wh_b, Ww_w, Ww_b,
                                        M16, Wc16, cbv);
    gram<<<dim3(8, 14, 5), 256, 0, stream>>>(xb, Gbuf);
    sandwich<<<dim3(14, 9), 256, 0, stream>>>(
        thc_w, phc_w, thc_b, phc_b, thh_w, phh_w, thh_b, phh_b,
        thw_w, phw_w, thw_b, phw_b, Gbuf, sbuf, f1b, f2b);
    softmax_all<<<42, 256, 0, stream>>>(f1b, f2b, f16_1, f16_23);
    kmat<<<dim3(14, 3), 256, 0, stream>>>(f16_1, f16_23, gc_w, gc_b, gh_w, gh_b, gw_w, gw_b,
                                          K1, B1, K2, B2);
    fold_res<<<256, 256, 0, stream>>>(Wc16, xT, out);
    pv1k<<<dim3(64, 1, BURST), 256, 0, stream>>>(xT, K1, B1, y1);
    pv23k<<<dim3(32, 2, 2 * BURST), 256, 0, stream>>>(xT, K2, B2, y2, y3);
    yfold<<<dim3(128, 2, 3), 256, 0, stream>>>(M16, y1, y2, y3, out);
    leaky_cb<<<1024, 256, 0, stream>>>(out, cbv);
}

// Round 5
// 360.084 us; speedup vs baseline: 4.6398x; 1.3447x over previous
//
#include <hip/hip_runtime.h>

#define NF 64
#define BURST 14
#define NPIX 16384
#define CN (NF * NPIX)
#define LP 72

typedef short bf16x8 __attribute__((ext_vector_type(8)));
typedef float f32x4 __attribute__((ext_vector_type(4)));
typedef unsigned short us4 __attribute__((ext_vector_type(4)));

__device__ inline unsigned short f2bf(float f) {
    unsigned int u = __float_as_uint(f);
    return (unsigned short)((u + 0x7fffu + ((u >> 16) & 1u)) >> 16);
}
__device__ inline float bf2f(unsigned short u) {
    return __uint_as_float(((unsigned int)u) << 16);
}

// ---------------------------------------------------------------------------
// x fp32 [b][c][pix] -> xb bf16 same layout + xT bf16 [b][pix][c] + half sums
// S[b][dlt][c] = sum_{k<8192} x[c][dlt*8192+k]  (atomic fp32, pre-zeroed)
// grid (128, 14), block 256
// ---------------------------------------------------------------------------
__global__ __launch_bounds__(256) void cast_x(const float* __restrict__ X,
                                              unsigned short* __restrict__ XB,
                                              unsigned short* __restrict__ XT,
                                              float* __restrict__ S)
{
    __shared__ unsigned short Xs[128][LP];
    const int tid = threadIdx.x;
    const int p0 = blockIdx.x * 128;
    const int b = blockIdx.y;
    const size_t boff = (size_t)b * CN;
#pragma unroll
    for (int i = 0; i < 8; ++i) {
        const int id = tid + 256 * i;
        const int c = id >> 5, p4 = (id & 31) * 4;
        float4 v = *(const float4*)&X[boff + (size_t)c * NPIX + p0 + p4];
        us4 r;
        r.x = f2bf(v.x); r.y = f2bf(v.y); r.z = f2bf(v.z); r.w = f2bf(v.w);
        *(us4*)&XB[boff + (size_t)c * NPIX + p0 + p4] = r;
        Xs[p4 + 0][c] = r.x; Xs[p4 + 1][c] = r.y;
        Xs[p4 + 2][c] = r.z; Xs[p4 + 3][c] = r.w;
    }
    __syncthreads();
#pragma unroll
    for (int i = 0; i < 4; ++i) {
        const int id = tid + 256 * i;
        const int row = id >> 3, c8 = (id & 7) * 8;
        *(bf16x8*)&XT[boff + (size_t)(p0 + row) * 64 + c8] = *(const bf16x8*)&Xs[row][c8];
    }
    if (tid < 64) {
        float sv = 0.f;
        for (int pp = 0; pp < 128; ++pp) sv += bf2f(Xs[pp][tid]);
        atomicAdd(&S[(b * 2 + (p0 >= 8192 ? 1 : 0)) * 64 + tid], sv);
    }
}

// ---------------------------------------------------------------------------
// Precompute, every block fully parallel:
//  blocks 0..41  : M16[g][b] = bf16(Fsub @ Wg)
//  blocks 42..97 : Wc16 (1024 elements each)
//  blocks 98..105: cb (8 o-rows each, lane-parallel over ch)
//  blocks 106..108: gT16[g][c'][d] = bf16(wg[d*64+c'])  (transposed g weights)
// ---------------------------------------------------------------------------
__global__ __launch_bounds__(256) void precompute(
    const float* __restrict__ fus_w, const float* __restrict__ fus_b,
    const float* __restrict__ Wc, const float* __restrict__ bWc,
    const float* __restrict__ Wh, const float* __restrict__ bWh,
    const float* __restrict__ Ww, const float* __restrict__ bWw,
    const float* __restrict__ gcw, const float* __restrict__ ghw,
    const float* __restrict__ gww,
    unsigned short* __restrict__ M16, unsigned short* __restrict__ Wc16,
    float* __restrict__ cb, unsigned short* __restrict__ gT16)
{
    const int blk = blockIdx.x, tid = threadIdx.x;
    if (blk < 42) {
        __shared__ float Fl[64][65];
        __shared__ float Wl[64][65];
        const int g = blk / 14, b = blk % 14;
        const float* Wg = (g == 0) ? Wc : (g == 1) ? Wh : Ww;
#pragma unroll
        for (int i = 0; i < 4; ++i) {
            const int id = tid + 256 * i;
            const int r = id >> 4, c4 = (id & 15) * 4;
            float4 v = *(const float4*)&fus_w[r * 2688 + g * 896 + b * 64 + c4];
            Fl[r][c4] = v.x; Fl[r][c4 + 1] = v.y; Fl[r][c4 + 2] = v.z; Fl[r][c4 + 3] = v.w;
            float4 u = *(const float4*)&Wg[r * 64 + c4];
            Wl[r][c4] = u.x; Wl[r][c4 + 1] = u.y; Wl[r][c4 + 2] = u.z; Wl[r][c4 + 3] = u.w;
        }
        __syncthreads();
        const int o = tid & 63, qq = tid >> 6;
        float s[16];
#pragma unroll
        for (int i = 0; i < 16; ++i) s[i] = 0.f;
        for (int c2 = 0; c2 < 64; ++c2) {
            const float fv = Fl[o][c2];
#pragma unroll
            for (int i = 0; i < 16; ++i) s[i] += fv * Wl[c2][qq * 16 + i];
        }
        unsigned short* Mout = M16 + (size_t)blk * 4096;
#pragma unroll
        for (int i = 0; i < 16; i += 4) {
            us4 r4; r4.x = f2bf(s[i]); r4.y = f2bf(s[i + 1]); r4.z = f2bf(s[i + 2]); r4.w = f2bf(s[i + 3]);
            *(us4*)&Mout[o * 64 + qq * 16 + i] = r4;
        }
    } else if (blk < 98) {
        const int e0 = (blk - 42) * 1024 + tid * 4;
        const int o = e0 / 896, bc = e0 - o * 896;
        float4 a = *(const float4*)&fus_w[o * 2688 + bc];
        float4 b2 = *(const float4*)&fus_w[o * 2688 + 896 + bc];
        float4 c3 = *(const float4*)&fus_w[o * 2688 + 1792 + bc];
        us4 r;
        r.x = f2bf(a.x + b2.x + c3.x); r.y = f2bf(a.y + b2.y + c3.y);
        r.z = f2bf(a.z + b2.z + c3.z); r.w = f2bf(a.w + b2.w + c3.w);
        *(us4*)&Wc16[e0] = r;
    } else if (blk < 106) {
        __shared__ float red[256];
        const int o = (blk - 98) * 8 + (tid >> 5);
        const int lane = tid & 31;
        float s = 0.f;
        for (int t = 0; t < 84; ++t) {
            const int ch = lane + 32 * t;
            const int g = ch / 896, c2 = ch & 63;
            const float bg = (g == 0) ? bWc[c2] : (g == 1) ? bWh[c2] : bWw[c2];
            s += fus_w[o * 2688 + ch] * bg;
        }
        red[tid] = s;
        __syncthreads();
        if (tid < 8) {
            const int oo = (blk - 98) * 8 + tid;
            float t = fus_b[oo];
            for (int i = 0; i < 32; ++i) t += red[tid * 32 + i];
            cb[oo] = t;
        }
    } else {
        const int g = blk - 106;
        const float* wg = (g == 0) ? gcw : (g == 1) ? ghw : gww;
        unsigned short* dst = gT16 + (size_t)g * 4096;
        for (int e = tid; e < 4096; e += 256) {
            const int cp = e >> 6, d = e & 63;
            dst[e] = f2bf(wg[d * 64 + cp]);
        }
    }
}

// ---------------------------------------------------------------------------
// Gram kernel: G[b][z][c][c'] (fp32 atomics, pre-zeroed)
// grid (8, 14, 5), block 256
// ---------------------------------------------------------------------------
__global__ __launch_bounds__(256) void gram(
    const unsigned short* __restrict__ XB, float* __restrict__ G)
{
    const int tid = threadIdx.x;
    const int w = tid >> 6, l = tid & 63, lm = l & 15, q = l >> 4;
    const int b = blockIdx.y, z = blockIdx.z;
    const unsigned short* A;
    const unsigned short* B;
    int k0, ksteps;
    if (z == 0) {
        A = XB + (size_t)b * CN; B = A;
        k0 = blockIdx.x * 2048; ksteps = 64;
    } else {
        const int dl = (z - 1) >> 1, dp = (z - 1) & 1;
        A = XB + (size_t)dl * 8192;
        B = XB + (size_t)b * CN + (size_t)dp * 8192;
        k0 = blockIdx.x * 1024; ksteps = 32;
    }
    const int mo = (w & 1) * 32, no = (w >> 1) * 32;
    f32x4 acc[2][2] = {};
    for (int ks = 0; ks < ksteps; ++ks) {
        const int k = k0 + ks * 32 + q * 8;
        bf16x8 a[2], bb[2];
#pragma unroll
        for (int mi = 0; mi < 2; ++mi) a[mi] = *(const bf16x8*)&A[(size_t)(mo + mi * 16 + lm) * NPIX + k];
#pragma unroll
        for (int ni = 0; ni < 2; ++ni) bb[ni] = *(const bf16x8*)&B[(size_t)(no + ni * 16 + lm) * NPIX + k];
#pragma unroll
        for (int mi = 0; mi < 2; ++mi)
#pragma unroll
            for (int ni = 0; ni < 2; ++ni)
                acc[mi][ni] = __builtin_amdgcn_mfma_f32_16x16x32_bf16(a[mi], bb[ni], acc[mi][ni], 0, 0, 0);
    }
    float* Gp = G + (size_t)(b * 5 + z) * 4096;
#pragma unroll
    for (int mi = 0; mi < 2; ++mi)
#pragma unroll
        for (int r = 0; r < 4; ++r)
#pragma unroll
            for (int ni = 0; ni < 2; ++ni)
                atomicAdd(&Gp[(mo + mi * 16 + q * 4 + r) * 64 + no + ni * 16 + lm], acc[mi][ni][r]);
}

// ---------------------------------------------------------------------------
// Sandwich: logits from Grams (fp32).  grid (14, 9), block 256
// ---------------------------------------------------------------------------
__global__ __launch_bounds__(256) void sandwich(
    const float* __restrict__ thc_w, const float* __restrict__ phc_w,
    const float* __restrict__ thc_b, const float* __restrict__ phc_b,
    const float* __restrict__ thh_w, const float* __restrict__ phh_w,
    const float* __restrict__ thh_b, const float* __restrict__ phh_b,
    const float* __restrict__ thw_w, const float* __restrict__ phw_w,
    const float* __restrict__ thw_b, const float* __restrict__ phw_b,
    const float* __restrict__ G, const float* __restrict__ S,
    float* __restrict__ f1, float* __restrict__ f2)
{
    __shared__ float Wt[64][65], Wp[64][65], Gl[64][65], Tl[64][65];
    __shared__ float sth[64], sph[64], uu[64], vv[64], btl[64], bpl[64];
    const int b = blockIdx.x, y = blockIdx.y, tid = threadIdx.x;
    const float *Wth_g, *Wph_g, *bth_g, *bph_g, *Gp;
    float* outp; int dl = 0, dp = 0; float Kn;
    if (y == 0) {
        Wth_g = thc_w; Wph_g = phc_w; bth_g = thc_b; bph_g = phc_b;
        Gp = G + (size_t)(b * 5) * 4096; Kn = 16384.f;
        outp = f1 + (size_t)b * 4096;
    } else {
        const int part = (y - 1) / 4, e = (y - 1) & 3;
        dl = e >> 1; dp = e & 1;
        if (part == 0) { Wth_g = thh_w; Wph_g = phh_w; bth_g = thh_b; bph_g = phh_b; }
        else           { Wth_g = thw_w; Wph_g = phw_w; bth_g = thw_b; bph_g = phw_b; }
        Gp = G + (size_t)(b * 5 + 1 + e) * 4096; Kn = 8192.f;
        outp = f2 + (size_t)(part * 14 + b) * 16384;
    }
#pragma unroll
    for (int i = 0; i < 4; ++i) {
        const int id = tid + 256 * i;
        const int r = id >> 4, c4 = (id & 15) * 4;
        float4 v = *(const float4*)&Wth_g[r * 64 + c4];
        Wt[r][c4] = v.x; Wt[r][c4 + 1] = v.y; Wt[r][c4 + 2] = v.z; Wt[r][c4 + 3] = v.w;
        float4 u = *(const float4*)&Wph_g[r * 64 + c4];
        Wp[r][c4] = u.x; Wp[r][c4 + 1] = u.y; Wp[r][c4 + 2] = u.z; Wp[r][c4 + 3] = u.w;
        float4 g = *(const float4*)&Gp[r * 64 + c4];
        Gl[r][c4] = g.x; Gl[r][c4 + 1] = g.y; Gl[r][c4 + 2] = g.z; Gl[r][c4 + 3] = g.w;
    }
    if (tid < 64) {
        if (y == 0) { const float sf = S[b * 128 + tid] + S[b * 128 + 64 + tid]; sth[tid] = sf; sph[tid] = sf; }
        else { sth[tid] = S[dl * 64 + tid]; sph[tid] = S[b * 128 + dp * 64 + tid]; }
        btl[tid] = bth_g[tid]; bpl[tid] = bph_g[tid];
    }
    __syncthreads();
    if (tid < 64) {
        float su = 0.f, sv = 0.f;
        for (int c = 0; c < 64; ++c) { su += Wt[tid][c] * sth[c]; sv += Wp[tid][c] * sph[c]; }
        uu[tid] = su; vv[tid] = sv;
    }
    const int t = tid & 63, qq = tid >> 6;
    float r16[16];
#pragma unroll
    for (int i = 0; i < 16; ++i) r16[i] = 0.f;
    for (int c = 0; c < 64; ++c) {
        const float fv = Wt[t][c];
#pragma unroll
        for (int i = 0; i < 16; ++i) r16[i] += fv * Gl[c][qq * 16 + i];
    }
#pragma unroll
    for (int i = 0; i < 16; ++i) Tl[t][qq * 16 + i] = r16[i];
    __syncthreads();
#pragma unroll
    for (int i = 0; i < 16; ++i) r16[i] = 0.f;
    for (int c = 0; c < 64; ++c) {
        const float tv = Tl[t][c];
#pragma unroll
        for (int i = 0; i < 16; ++i) r16[i] += tv * Wp[qq * 16 + i][c];
    }
    if (y == 0) {
#pragma unroll
        for (int i = 0; i < 16; ++i) {
            const int d = qq * 16 + i;
            outp[t * 64 + d] = r16[i] + uu[t] * bpl[d] + btl[t] * vv[d] + Kn * btl[t] * bpl[d];
        }
    } else {
#pragma unroll
        for (int i = 0; i < 16; ++i) {
            const int tp = qq * 16 + i;
            outp[(2 * t + dl) * 128 + 2 * tp + dp] =
                r16[i] + uu[t] * bpl[tp] + btl[t] * vv[tp] + Kn * btl[t] * bpl[tp];
        }
    }
}

// ---------------------------------------------------------------------------
// Merged softmax + bias dots + de-interleave:
//  blocks 0..13: part1 (64x64, over c for fixed d) -> o1[b][c*64+d], B1[b][c]
//  blocks 14..41: parts 2/3 (128x128, over i for fixed j)
//    -> o2d[(idx*2+dlt)*8192 + i*64 + t] (t=j>>1, dlt=j&1),  B2[idx*128+i]
// ---------------------------------------------------------------------------
__global__ __launch_bounds__(256) void softmax_all(
    const float* __restrict__ f1, const float* __restrict__ f2,
    const float* __restrict__ gcb, const float* __restrict__ ghb,
    const float* __restrict__ gwb,
    unsigned short* __restrict__ o1, unsigned short* __restrict__ o2d,
    float* __restrict__ B1, float* __restrict__ B2)
{
    __shared__ float red[256];
    __shared__ float mxA[128], invA[128];
    __shared__ float bgl[64];
    const int bx = blockIdx.x, tid = threadIdx.x;
    if (bx < 14) {
        const float* Fb = f1 + (size_t)bx * 4096;
        unsigned short* Ob = o1 + (size_t)bx * 4096;
        if (tid < 64) bgl[tid] = gcb[tid];
        const int d = tid & 63, qq = tid >> 6;
        float mx = -1e30f;
        for (int c = qq * 16; c < qq * 16 + 16; ++c) mx = fmaxf(mx, Fb[c * 64 + d]);
        red[tid] = mx;
        __syncthreads();
        if (tid < 64) mxA[tid] = fmaxf(fmaxf(red[tid], red[64 + tid]), fmaxf(red[128 + tid], red[192 + tid]));
        __syncthreads();
        const float m = mxA[d];
        float s = 0.f;
        for (int c = qq * 16; c < qq * 16 + 16; ++c) s += __expf(Fb[c * 64 + d] - m);
        red[tid] = s;
        __syncthreads();
        if (tid < 64) invA[tid] = 1.f / (red[tid] + red[64 + tid] + red[128 + tid] + red[192 + tid]);
        __syncthreads();
        const int e0 = tid * 16;
        const int d0 = e0 & 63;
        float bp = 0.f;
#pragma unroll
        for (int i = 0; i < 16; i += 4) {
            us4 r4;
            float v0 = __expf(Fb[e0 + i] - mxA[d0 + i]) * invA[d0 + i];
            float v1 = __expf(Fb[e0 + i + 1] - mxA[d0 + i + 1]) * invA[d0 + i + 1];
            float v2 = __expf(Fb[e0 + i + 2] - mxA[d0 + i + 2]) * invA[d0 + i + 2];
            float v3 = __expf(Fb[e0 + i + 3] - mxA[d0 + i + 3]) * invA[d0 + i + 3];
            bp += v0 * bgl[d0 + i] + v1 * bgl[d0 + i + 1] + v2 * bgl[d0 + i + 2] + v3 * bgl[d0 + i + 3];
            r4.x = f2bf(v0); r4.y = f2bf(v1); r4.z = f2bf(v2); r4.w = f2bf(v3);
            *(us4*)&Ob[e0 + i] = r4;
        }
        red[tid] = bp;
        __syncthreads();
        if (tid < 64)
            B1[bx * 64 + tid] = red[tid * 4] + red[tid * 4 + 1] + red[tid * 4 + 2] + red[tid * 4 + 3];
    } else {
        const int idx = bx - 14;
        const float* Fb = f2 + (size_t)idx * 16384;
        if (tid < 64) bgl[tid] = (idx < 14) ? ghb[tid] : gwb[tid];
        const int j = tid & 127, ih = tid >> 7;
        float mx = -1e30f;
        for (int i = ih * 64; i < ih * 64 + 64; ++i) mx = fmaxf(mx, Fb[i * 128 + j]);
        red[tid] = mx;
        __syncthreads();
        if (tid < 128) mxA[tid] = fmaxf(red[tid], red[128 + tid]);
        __syncthreads();
        const float m = mxA[j];
        float s = 0.f;
        for (int i = ih * 64; i < ih * 64 + 64; ++i) s += __expf(Fb[i * 128 + j] - m);
        red[tid] = s;
        __syncthreads();
        if (tid < 128) invA[tid] = 1.f / (red[tid] + red[128 + tid]);
        __syncthreads();
        const int e0 = tid * 64;
        const int irow = tid >> 1;
        const int j0 = e0 & 127;
        unsigned short vt[2][32];
        float bp = 0.f;
        for (int ii = 0; ii < 64; ++ii) {
            const int jj = j0 + ii;
            const float v = __expf(Fb[e0 + ii] - mxA[jj]) * invA[jj];
            bp += v * bgl[jj >> 1];
            vt[jj & 1][ii >> 1] = f2bf(v);
        }
        unsigned short* Od = o2d + (size_t)idx * 16384 + irow * 64 + (j0 >> 1);
#pragma unroll
        for (int dlt = 0; dlt < 2; ++dlt)
#pragma unroll
            for (int ss = 0; ss < 32; ss += 4)
                *(us4*)&Od[dlt * 8192 + ss] = *(us4*)&vt[dlt][ss];
        red[tid] = bp;
        __syncthreads();
        if (tid < 128) B2[idx * 128 + tid] = red[2 * tid] + red[2 * tid + 1];
    }
}

// ---------------------------------------------------------------------------
// kmat via MFMA, LDS-free:
//  y=0: K1[b][c][c'] = sum_d f1[c][d] gT16[0][c'][d]         (64x64x64)
//  y=1/2: K2[part][b][dlt][i][c] = sum_t f2d[dlt][i][t] gT16[1+part][c][t]
// grid (14, 3), block 256
// ---------------------------------------------------------------------------
__global__ __launch_bounds__(256) void kmat(
    const unsigned short* __restrict__ f16_1, const unsigned short* __restrict__ f2d,
    const unsigned short* __restrict__ gT16,
    unsigned short* __restrict__ K1, unsigned short* __restrict__ K2)
{
    const int b = blockIdx.x, y = blockIdx.y, tid = threadIdx.x;
    const int w = tid >> 6, l = tid & 63, lm = l & 15, q = l >> 4;
    if (y == 0) {
        const unsigned short* A = f16_1 + (size_t)b * 4096;
        const unsigned short* Bm = gT16;
        const int mo = (w & 1) * 32, no = (w >> 1) * 32;
        f32x4 acc[2][2] = {};
#pragma unroll
        for (int ks = 0; ks < 2; ++ks) {
            const int k = ks * 32 + q * 8;
            bf16x8 a[2], bb[2];
#pragma unroll
            for (int mi = 0; mi < 2; ++mi) a[mi] = *(const bf16x8*)&A[(mo + mi * 16 + lm) * 64 + k];
#pragma unroll
            for (int ni = 0; ni < 2; ++ni) bb[ni] = *(const bf16x8*)&Bm[(no + ni * 16 + lm) * 64 + k];
#pragma unroll
            for (int mi = 0; mi < 2; ++mi)
#pragma unroll
                for (int ni = 0; ni < 2; ++ni)
                    acc[mi][ni] = __builtin_amdgcn_mfma_f32_16x16x32_bf16(a[mi], bb[ni], acc[mi][ni], 0, 0, 0);
        }
        unsigned short* Kp = K1 + (size_t)b * 4096;
#pragma unroll
        for (int mi = 0; mi < 2; ++mi)
#pragma unroll
            for (int r = 0; r < 4; ++r)
#pragma unroll
                for (int ni = 0; ni < 2; ++ni)
                    Kp[(mo + mi * 16 + q * 4 + r) * 64 + no + ni * 16 + lm] = f2bf(acc[mi][ni][r]);
    } else {
        const int part = y - 1;
        const unsigned short* Bm = gT16 + (size_t)(1 + part) * 4096;
        unsigned short* Kp = K2 + (size_t)(part * 14 + b) * 16384;
        for (int dlt = 0; dlt < 2; ++dlt) {
            const unsigned short* A = f2d + (size_t)(part * 14 + b) * 16384 + dlt * 8192;
            const int mo = (w & 1) * 64, no = (w >> 1) * 32;
            f32x4 acc[4][2] = {};
#pragma unroll
            for (int ks = 0; ks < 2; ++ks) {
                const int k = ks * 32 + q * 8;
                bf16x8 a[4], bb[2];
#pragma unroll
                for (int mi = 0; mi < 4; ++mi) a[mi] = *(const bf16x8*)&A[(mo + mi * 16 + lm) * 64 + k];
#pragma unroll
                for (int ni = 0; ni < 2; ++ni) bb[ni] = *(const bf16x8*)&Bm[(no + ni * 16 + lm) * 64 + k];
#pragma unroll
                for (int mi = 0; mi < 4; ++mi)
#pragma unroll
                    for (int ni = 0; ni < 2; ++ni)
                        acc[mi][ni] = __builtin_amdgcn_mfma_f32_16x16x32_bf16(a[mi], bb[ni], acc[mi][ni], 0, 0, 0);
            }
#pragma unroll
            for (int mi = 0; mi < 4; ++mi)
#pragma unroll
                for (int r = 0; r < 4; ++r)
#pragma unroll
                    for (int ni = 0; ni < 2; ++ni)
                        Kp[dlt * 8192 + (mo + mi * 16 + q * 4 + r) * 64 + no + ni * 16 + lm] = f2bf(acc[mi][ni][r]);
        }
    }
}

// ---------------------------------------------------------------------------
// Residual fold, LDS-free.  grid (256), block 256.
// ---------------------------------------------------------------------------
__global__ __launch_bounds__(256) void fold_res(
    const unsigned short* __restrict__ Wcomb, const unsigned short* __restrict__ XT,
    float* __restrict__ Out)
{
    const int tid = threadIdx.x;
    const int w = tid >> 6, l = tid & 63, lm = l & 15, q = l >> 4;
    const int p0 = blockIdx.x * 64 + (w >> 1) * 32;
    const int oh = (w & 1) * 32;
    f32x4 acc[2][2] = {};
    for (int b = 0; b < 14; ++b) {
#pragma unroll
        for (int ks = 0; ks < 2; ++ks) {
            const int c0 = ks * 32 + q * 8;
            bf16x8 a[2], bb[2];
#pragma unroll
            for (int mi = 0; mi < 2; ++mi)
                a[mi] = *(const bf16x8*)&Wcomb[(oh + mi * 16 + lm) * 896 + b * 64 + c0];
#pragma unroll
            for (int ni = 0; ni < 2; ++ni)
                bb[ni] = *(const bf16x8*)&XT[(size_t)b * CN + (size_t)(p0 + ni * 16 + lm) * 64 + c0];
#pragma unroll
            for (int mi = 0; mi < 2; ++mi)
#pragma unroll
                for (int ni = 0; ni < 2; ++ni)
                    acc[mi][ni] = __builtin_amdgcn_mfma_f32_16x16x32_bf16(a[mi], bb[ni], acc[mi][ni], 0, 0, 0);
        }
    }
#pragma unroll
    for (int mi = 0; mi < 2; ++mi)
#pragma unroll
        for (int r = 0; r < 4; ++r) {
            const int o = oh + mi * 16 + q * 4 + r;
#pragma unroll
            for (int ni = 0; ni < 2; ++ni)
                Out[(size_t)o * NPIX + p0 + ni * 16 + lm] = acc[mi][ni][r];
        }
}

// ---------------------------------------------------------------------------
// pv1: Y[p*64+c] = sum_{c'} xT[p][c'] K1[c][c'] + B1[c].  grid (64,1,14)
// ---------------------------------------------------------------------------
__global__ __launch_bounds__(256) void pv1k(
    const unsigned short* __restrict__ XT, const unsigned short* __restrict__ K1,
    const float* __restrict__ B1, unsigned short* __restrict__ Y)
{
    const int tid = threadIdx.x;
    const int w = tid >> 6, l = tid & 63, lm = l & 15, q = l >> 4;
    const int b = blockIdx.z;
    const int p0 = blockIdx.x * 256 + w * 64;
    const unsigned short* Xb = XT + (size_t)b * CN;
    const unsigned short* Kb = K1 + (size_t)b * 4096;
    f32x4 acc[4][4] = {};
#pragma unroll
    for (int ks = 0; ks < 2; ++ks) {
        const int c0 = ks * 32 + q * 8;
        bf16x8 a[4], bb[4];
#pragma unroll
        for (int mi = 0; mi < 4; ++mi) a[mi] = *(const bf16x8*)&Xb[(size_t)(p0 + mi * 16 + lm) * 64 + c0];
#pragma unroll
        for (int ni = 0; ni < 4; ++ni) bb[ni] = *(const bf16x8*)&Kb[(ni * 16 + lm) * 64 + c0];
#pragma unroll
        for (int mi = 0; mi < 4; ++mi)
#pragma unroll
            for (int ni = 0; ni < 4; ++ni)
                acc[mi][ni] = __builtin_amdgcn_mfma_f32_16x16x32_bf16(a[mi], bb[ni], acc[mi][ni], 0, 0, 0);
    }
    unsigned short* Yb = Y + (size_t)b * CN;
#pragma unroll
    for (int mi = 0; mi < 4; ++mi)
#pragma unroll
        for (int r = 0; r < 4; ++r) {
            const int p = p0 + mi * 16 + q * 4 + r;
#pragma unroll
            for (int ni = 0; ni < 4; ++ni) {
                const int c = ni * 16 + lm;
                Yb[(size_t)p * 64 + c] = f2bf(acc[mi][ni][r] + B1[b * 64 + c]);
            }
        }
}

// ---------------------------------------------------------------------------
// pv2/3: Y[k*128+i] = sum_dlt sum_c xT[dlt*8192+k][c] K2[dlt][i][c] + B2[i]
// grid (32, 2, 28)
// ---------------------------------------------------------------------------
__global__ __launch_bounds__(256) void pv23k(
    const unsigned short* __restrict__ XT, const unsigned short* __restrict__ K2,
    const float* __restrict__ B2, unsigned short* __restrict__ Y2,
    unsigned short* __restrict__ Y3)
{
    const int tid = threadIdx.x;
    const int w = tid >> 6, l = tid & 63, lm = l & 15, q = l >> 4;
    const int part = blockIdx.z / 14, b = blockIdx.z % 14;
    const int k00 = blockIdx.x * 256 + w * 64;
    const int i0 = blockIdx.y * 64;
    const unsigned short* Xb = XT + (size_t)b * CN;
    const unsigned short* Kb = K2 + (size_t)(part * 14 + b) * 16384;
    const float* Bb = B2 + (part * 14 + b) * 128;
    f32x4 acc[4][4] = {};
#pragma unroll
    for (int dlt = 0; dlt < 2; ++dlt) {
#pragma unroll
        for (int ks = 0; ks < 2; ++ks) {
            const int c0 = ks * 32 + q * 8;
            bf16x8 a[4], bb[4];
#pragma unroll
            for (int mi = 0; mi < 4; ++mi)
                a[mi] = *(const bf16x8*)&Xb[(size_t)(dlt * 8192 + k00 + mi * 16 + lm) * 64 + c0];
#pragma unroll
            for (int ni = 0; ni < 4; ++ni)
                bb[ni] = *(const bf16x8*)&Kb[dlt * 8192 + (i0 + ni * 16 + lm) * 64 + c0];
#pragma unroll
            for (int mi = 0; mi < 4; ++mi)
#pragma unroll
                for (int ni = 0; ni < 4; ++ni)
                    acc[mi][ni] = __builtin_amdgcn_mfma_f32_16x16x32_bf16(a[mi], bb[ni], acc[mi][ni], 0, 0, 0);
        }
    }
    unsigned short* Yb = (part ? Y3 : Y2) + (size_t)b * CN;
#pragma unroll
    for (int mi = 0; mi < 4; ++mi)
#pragma unroll
        for (int r = 0; r < 4; ++r) {
            const int k = k00 + mi * 16 + q * 4 + r;
#pragma unroll
            for (int ni = 0; ni < 4; ++ni) {
                const int ii = i0 + ni * 16 + lm;
                Yb[(size_t)k * 128 + ii] = f2bf(acc[mi][ni][r] + Bb[ii]);
            }
        }
}

// ---------------------------------------------------------------------------
// Merged y-fold: Out[o][pix] += sum_t M[z][t][o][c2] y_z[t][c2][pix]
// grid (128, 2, 3), block 256
// ---------------------------------------------------------------------------
__global__ __launch_bounds__(256) void yfold(
    const unsigned short* __restrict__ M16,
    const unsigned short* __restrict__ Y1, const unsigned short* __restrict__ Y2,
    const unsigned short* __restrict__ Y3, float* __restrict__ Out)
{
    __shared__ unsigned short As[64][LP];
    __shared__ unsigned short Ss[128][LP];
    const int tid = threadIdx.x;
    const int z = blockIdx.z;
    const unsigned short* Ap = M16 + (size_t)z * 14 * 4096;
    const unsigned short* S = (z == 0) ? Y1 : (z == 1) ? Y2 : Y3;
    const int p0 = blockIdx.x * 128;
    const int t0 = blockIdx.y * 7;
    const int w = tid >> 6, l = tid & 63, lm = l & 15, q = l >> 4;
    const int mo = (w & 1) * 32;
    const int no = (w >> 1) * 64;
    f32x4 acc[2][4] = {};

    for (int t = t0; t < t0 + 7; ++t) {
        __syncthreads();
#pragma unroll
        for (int i = 0; i < 2; ++i) {
            const int ch = tid + 256 * i;
            const int row = ch >> 3, c8 = (ch & 7) * 8;
            *(bf16x8*)&As[row][c8] = *(const bf16x8*)&Ap[(size_t)t * 4096 + (size_t)row * 64 + c8];
        }
#pragma unroll
        for (int i = 0; i < 4; ++i) {
            const int id = tid + 256 * i;
            const int c = id & 63, p8 = (id >> 6) * 8;
            bf16x8 v = *(const bf16x8*)&S[(size_t)t * CN + (size_t)c * NPIX + p0 + p8];
#pragma unroll
            for (int j = 0; j < 8; ++j) Ss[p8 + j][c] = (unsigned short)v[j];
        }
        __syncthreads();
#pragma unroll
        for (int ks = 0; ks < 2; ++ks) {
            const int c0 = ks * 32 + q * 8;
            bf16x8 a[2], bb[4];
#pragma unroll
            for (int mi = 0; mi < 2; ++mi) a[mi] = *(const bf16x8*)&As[mo + mi * 16 + lm][c0];
#pragma unroll
            for (int ni = 0; ni < 4; ++ni) bb[ni] = *(const bf16x8*)&Ss[no + ni * 16 + lm][c0];
#pragma unroll
            for (int mi = 0; mi < 2; ++mi)
#pragma unroll
                for (int ni = 0; ni < 4; ++ni)
                    acc[mi][ni] = __builtin_amdgcn_mfma_f32_16x16x32_bf16(a[mi], bb[ni], acc[mi][ni], 0, 0, 0);
        }
    }
#pragma unroll
    for (int mi = 0; mi < 2; ++mi)
#pragma unroll
        for (int r = 0; r < 4; ++r) {
            const int o = mo + mi * 16 + q * 4 + r;
#pragma unroll
            for (int ni = 0; ni < 4; ++ni)
                atomicAdd(&Out[(size_t)o * NPIX + p0 + no + ni * 16 + lm], acc[mi][ni][r]);
        }
}

// out = leaky(out + cb[o])
__global__ __launch_bounds__(256) void leaky_cb(float* __restrict__ O, const float* __restrict__ cb)
{
    const int i = blockIdx.x * 256 + threadIdx.x;
    float4 v = ((float4*)O)[i];
    const float b = cb[(i * 4) >> 14];
    v.x += b; v.y += b; v.z += b; v.w += b;
    v.x = v.x >= 0.f ? v.x : 0.2f * v.x;
    v.y = v.y >= 0.f ? v.y : 0.2f * v.y;
    v.z = v.z >= 0.f ? v.z : 0.2f * v.z;
    v.w = v.w >= 0.f ? v.w : 0.2f * v.w;
    ((float4*)O)[i] = v;
}

extern "C" void kernel_launch(void* const* d_in, const int* in_sizes, int n_in,
                              void* d_out, int out_size, void* d_ws, size_t ws_size,
                              hipStream_t stream)
{
    const float* x     = (const float*)d_in[0];
    const float* gc_w  = (const float*)d_in[1];
    const float* gc_b  = (const float*)d_in[2];
    const float* thc_w = (const float*)d_in[3];
    const float* thc_b = (const float*)d_in[4];
    const float* phc_w = (const float*)d_in[5];
    const float* phc_b = (const float*)d_in[6];
    const float* Wc_w  = (const float*)d_in[7];
    const float* Wc_b  = (const float*)d_in[8];
    const float* gh_w  = (const float*)d_in[9];
    const float* gh_b  = (const float*)d_in[10];
    const float* thh_w = (const float*)d_in[11];
    const float* thh_b = (const float*)d_in[12];
    const float* phh_w = (const float*)d_in[13];
    const float* phh_b = (const float*)d_in[14];
    const float* Wh_w  = (const float*)d_in[15];
    const float* Wh_b  = (const float*)d_in[16];
    const float* gw_w  = (const float*)d_in[17];
    const float* gw_b  = (const float*)d_in[18];
    const float* thw_w = (const float*)d_in[19];
    const float* thw_b = (const float*)d_in[20];
    const float* phw_w = (const float*)d_in[21];
    const float* phw_b = (const float*)d_in[22];
    const float* Ww_w  = (const float*)d_in[23];
    const float* Ww_b  = (const float*)d_in[24];
    const float* fus_w = (const float*)d_in[25];
    const float* fus_b = (const float*)d_in[26];

    float* out = (float*)d_out;

    char* p = (char*)d_ws;
    unsigned short* xb   = (unsigned short*)p; p += (size_t)BURST * CN * 2;
    unsigned short* xT   = (unsigned short*)p; p += (size_t)BURST * CN * 2;
    unsigned short* y1   = (unsigned short*)p; p += (size_t)BURST * CN * 2;
    unsigned short* y2   = (unsigned short*)p; p += (size_t)BURST * CN * 2;
    unsigned short* y3   = (unsigned short*)p; p += (size_t)BURST * CN * 2;
    float*          Gbuf = (float*)p;          p += (size_t)BURST * 5 * 4096 * 4;
    float*          sbuf = (float*)p;          p += (size_t)BURST * 2 * 64 * 4;
    float*          f1b  = (float*)p;          p += (size_t)BURST * 4096 * 4;
    float*          f2b  = (float*)p;          p += (size_t)2 * BURST * 16384 * 4;
    unsigned short* f16_1 = (unsigned short*)p; p += (size_t)BURST * 4096 * 2;
    unsigned short* f2d  = (unsigned short*)p; p += (size_t)2 * BURST * 16384 * 2;
    unsigned short* K1   = (unsigned short*)p; p += (size_t)BURST * 4096 * 2;
    unsigned short* K2   = (unsigned short*)p; p += (size_t)2 * BURST * 16384 * 2;
    float*          B1   = (float*)p;          p += (size_t)BURST * 64 * 4;
    float*          B2   = (float*)p;          p += (size_t)2 * BURST * 128 * 4;
    unsigned short* M16  = (unsigned short*)p; p += (size_t)42 * 4096 * 2;
    unsigned short* Wc16 = (unsigned short*)p; p += (size_t)64 * 896 * 2;
    unsigned short* gT16 = (unsigned short*)p; p += (size_t)3 * 4096 * 2;
    float*          cbv  = (float*)p;          p += 256;

    hipMemsetAsync(Gbuf, 0, ((size_t)BURST * 5 * 4096 + (size_t)BURST * 2 * 64) * 4, stream);

    cast_x<<<dim3(128, 14), 256, 0, stream>>>(x, xb, xT, sbuf);
    precompute<<<109, 256, 0, stream>>>(fus_w, fus_b, Wc_w, Wc_b, Wh_w, Wh_b, Ww_w, Ww_b,
                                        gc_w, gh_w, gw_w, M16, Wc16, cbv, gT16);
    gram<<<dim3(8, 14, 5), 256, 0, stream>>>(xb, Gbuf);
    sandwich<<<dim3(14, 9), 256, 0, stream>>>(
        thc_w, phc_w, thc_b, phc_b, thh_w, phh_w, thh_b, phh_b,
        thw_w, phw_w, thw_b, phw_b, Gbuf, sbuf, f1b, f2b);
    softmax_all<<<42, 256, 0, stream>>>(f1b, f2b, gc_b, gh_b, gw_b,
                                        f16_1, f2d, B1, B2);
    kmat<<<dim3(14, 3), 256, 0, stream>>>(f16_1, f2d, gT16, K1, K2);
    fold_res<<<256, 256, 0, stream>>>(Wc16, xT, out);
    pv1k<<<dim3(64, 1, BURST), 256, 0, stream>>>(xT, K1, B1, y1);
    pv23k<<<dim3(32, 2, 2 * BURST), 256, 0, stream>>>(xT, K2, B2, y2, y3);
    yfold<<<dim3(128, 2, 3), 256, 0, stream>>>(M16, y1, y2, y3, out);
    leaky_cb<<<1024, 256, 0, stream>>>(out, cbv);
}

// Round 6
// 331.026 us; speedup vs baseline: 5.0471x; 1.0878x over previous
//
#include <hip/hip_runtime.h>

#define NF 64
#define BURST 14
#define NPIX 16384
#define CN (NF * NPIX)
#define LP 72

typedef short bf16x8 __attribute__((ext_vector_type(8)));
typedef float f32x4 __attribute__((ext_vector_type(4)));
typedef unsigned short us4 __attribute__((ext_vector_type(4)));

__device__ inline unsigned short f2bf(float f) {
    unsigned int u = __float_as_uint(f);
    return (unsigned short)((u + 0x7fffu + ((u >> 16) & 1u)) >> 16);
}
__device__ inline float bf2f(unsigned short u) {
    return __uint_as_float(((unsigned int)u) << 16);
}

// ---------------------------------------------------------------------------
// x fp32 [b][c][pix] -> xb bf16 same layout + xT bf16 [b][pix][c] + half sums
// S[b][dlt][c] = sum_{k<8192} x[c][dlt*8192+k]  (atomic fp32, pre-zeroed)
// grid (128, 14), block 256
// ---------------------------------------------------------------------------
__global__ __launch_bounds__(256) void cast_x(const float* __restrict__ X,
                                              unsigned short* __restrict__ XB,
                                              unsigned short* __restrict__ XT,
                                              float* __restrict__ S)
{
    __shared__ unsigned short Xs[128][LP];
    __shared__ float red[256];
    const int tid = threadIdx.x;
    const int p0 = blockIdx.x * 128;
    const int b = blockIdx.y;
    const size_t boff = (size_t)b * CN;
#pragma unroll
    for (int i = 0; i < 8; ++i) {
        const int id = tid + 256 * i;
        const int c = id >> 5, p4 = (id & 31) * 4;
        float4 v = *(const float4*)&X[boff + (size_t)c * NPIX + p0 + p4];
        us4 r;
        r.x = f2bf(v.x); r.y = f2bf(v.y); r.z = f2bf(v.z); r.w = f2bf(v.w);
        *(us4*)&XB[boff + (size_t)c * NPIX + p0 + p4] = r;
        Xs[p4 + 0][c] = r.x; Xs[p4 + 1][c] = r.y;
        Xs[p4 + 2][c] = r.z; Xs[p4 + 3][c] = r.w;
    }
    __syncthreads();
#pragma unroll
    for (int i = 0; i < 4; ++i) {
        const int id = tid + 256 * i;
        const int row = id >> 3, c8 = (id & 7) * 8;
        *(bf16x8*)&XT[boff + (size_t)(p0 + row) * 64 + c8] = *(const bf16x8*)&Xs[row][c8];
    }
    {
        const int c = tid & 63, qq = tid >> 6;
        float sv = 0.f;
        for (int pp = qq * 32; pp < qq * 32 + 32; ++pp) sv += bf2f(Xs[pp][c]);
        red[tid] = sv;
        __syncthreads();
        if (tid < 64) {
            const float t = red[tid] + red[64 + tid] + red[128 + tid] + red[192 + tid];
            atomicAdd(&S[(b * 2 + (p0 >= 8192 ? 1 : 0)) * 64 + tid], t);
        }
    }
}

// ---------------------------------------------------------------------------
// Precompute, every block fully parallel:
//  blocks 0..41  : M16[g][b] = bf16(Fsub @ Wg)
//  blocks 42..97 : Wc16 (1024 elements each)
//  blocks 98..105: cb (8 o-rows each, lane-parallel over ch)
//  blocks 106..108: gT16[g][c'][d] = bf16(wg[d*64+c'])  (transposed g weights)
// ---------------------------------------------------------------------------
__global__ __launch_bounds__(256) void precompute(
    const float* __restrict__ fus_w, const float* __restrict__ fus_b,
    const float* __restrict__ Wc, const float* __restrict__ bWc,
    const float* __restrict__ Wh, const float* __restrict__ bWh,
    const float* __restrict__ Ww, const float* __restrict__ bWw,
    const float* __restrict__ gcw, const float* __restrict__ ghw,
    const float* __restrict__ gww,
    unsigned short* __restrict__ M16, unsigned short* __restrict__ Wc16,
    float* __restrict__ cb, unsigned short* __restrict__ gT16)
{
    const int blk = blockIdx.x, tid = threadIdx.x;
    if (blk < 42) {
        __shared__ float Fl[64][65];
        __shared__ float Wl[64][65];
        const int g = blk / 14, b = blk % 14;
        const float* Wg = (g == 0) ? Wc : (g == 1) ? Wh : Ww;
#pragma unroll
        for (int i = 0; i < 4; ++i) {
            const int id = tid + 256 * i;
            const int r = id >> 4, c4 = (id & 15) * 4;
            float4 v = *(const float4*)&fus_w[r * 2688 + g * 896 + b * 64 + c4];
            Fl[r][c4] = v.x; Fl[r][c4 + 1] = v.y; Fl[r][c4 + 2] = v.z; Fl[r][c4 + 3] = v.w;
            float4 u = *(const float4*)&Wg[r * 64 + c4];
            Wl[r][c4] = u.x; Wl[r][c4 + 1] = u.y; Wl[r][c4 + 2] = u.z; Wl[r][c4 + 3] = u.w;
        }
        __syncthreads();
        const int o = tid & 63, qq = tid >> 6;
        float s[16];
#pragma unroll
        for (int i = 0; i < 16; ++i) s[i] = 0.f;
        for (int c2 = 0; c2 < 64; ++c2) {
            const float fv = Fl[o][c2];
#pragma unroll
            for (int i = 0; i < 16; ++i) s[i] += fv * Wl[c2][qq * 16 + i];
        }
        unsigned short* Mout = M16 + (size_t)blk * 4096;
#pragma unroll
        for (int i = 0; i < 16; i += 4) {
            us4 r4; r4.x = f2bf(s[i]); r4.y = f2bf(s[i + 1]); r4.z = f2bf(s[i + 2]); r4.w = f2bf(s[i + 3]);
            *(us4*)&Mout[o * 64 + qq * 16 + i] = r4;
        }
    } else if (blk < 98) {
        const int e0 = (blk - 42) * 1024 + tid * 4;
        const int o = e0 / 896, bc = e0 - o * 896;
        float4 a = *(const float4*)&fus_w[o * 2688 + bc];
        float4 b2 = *(const float4*)&fus_w[o * 2688 + 896 + bc];
        float4 c3 = *(const float4*)&fus_w[o * 2688 + 1792 + bc];
        us4 r;
        r.x = f2bf(a.x + b2.x + c3.x); r.y = f2bf(a.y + b2.y + c3.y);
        r.z = f2bf(a.z + b2.z + c3.z); r.w = f2bf(a.w + b2.w + c3.w);
        *(us4*)&Wc16[e0] = r;
    } else if (blk < 106) {
        __shared__ float red[256];
        const int o = (blk - 98) * 8 + (tid >> 5);
        const int lane = tid & 31;
        float s = 0.f;
        for (int t = 0; t < 84; ++t) {
            const int ch = lane + 32 * t;
            const int g = ch / 896, c2 = ch & 63;
            const float bg = (g == 0) ? bWc[c2] : (g == 1) ? bWh[c2] : bWw[c2];
            s += fus_w[o * 2688 + ch] * bg;
        }
        red[tid] = s;
        __syncthreads();
        if (tid < 8) {
            const int oo = (blk - 98) * 8 + tid;
            float t = fus_b[oo];
            for (int i = 0; i < 32; ++i) t += red[tid * 32 + i];
            cb[oo] = t;
        }
    } else {
        const int g = blk - 106;
        const float* wg = (g == 0) ? gcw : (g == 1) ? ghw : gww;
        unsigned short* dst = gT16 + (size_t)g * 4096;
        for (int e = tid; e < 4096; e += 256) {
            const int cp = e >> 6, d = e & 63;
            dst[e] = f2bf(wg[d * 64 + cp]);
        }
    }
}

// ---------------------------------------------------------------------------
// Merged Gram: one block per (k-chunk of 256 in half-K, b).
// Loads batch0 rows (both halves) + batch-b rows (both halves) once, computes
// all 5 Gram variants: z0 self (half-paired), z1..4 cross (dl,dp).
// Writes per-block partials Gpart[(ks*14+b)*5*4096 ...] — no atomics.
// grid (32, 14), block 256
// ---------------------------------------------------------------------------
__global__ __launch_bounds__(256) void gram(
    const unsigned short* __restrict__ XB, float* __restrict__ Gpart)
{
    const int tid = threadIdx.x;
    const int w = tid >> 6, l = tid & 63, lm = l & 15, q = l >> 4;
    const int b = blockIdx.y;
    const int mo = (w & 1) * 32, no = (w >> 1) * 32;
    const unsigned short* P = XB;                    // batch 0
    const unsigned short* Q = XB + (size_t)b * CN;   // batch b
    f32x4 a0[2][2] = {}, a1[2][2] = {}, a2[2][2] = {}, a3[2][2] = {}, a4[2][2] = {};
#pragma unroll 2
    for (int ki = 0; ki < 8; ++ki) {
        const int k = blockIdx.x * 256 + ki * 32 + q * 8;
        bf16x8 p0[2], p1[2], qm0[2], qm1[2], qn0[2], qn1[2];
#pragma unroll
        for (int mi = 0; mi < 2; ++mi) {
            const size_t rm = (size_t)(mo + mi * 16 + lm) * NPIX;
            const size_t rn = (size_t)(no + mi * 16 + lm) * NPIX;
            p0[mi]  = *(const bf16x8*)&P[rm + k];
            p1[mi]  = *(const bf16x8*)&P[rm + 8192 + k];
            qm0[mi] = *(const bf16x8*)&Q[rm + k];
            qm1[mi] = *(const bf16x8*)&Q[rm + 8192 + k];
            qn0[mi] = *(const bf16x8*)&Q[rn + k];
            qn1[mi] = *(const bf16x8*)&Q[rn + 8192 + k];
        }
#pragma unroll
        for (int mi = 0; mi < 2; ++mi)
#pragma unroll
            for (int ni = 0; ni < 2; ++ni) {
                a0[mi][ni] = __builtin_amdgcn_mfma_f32_16x16x32_bf16(qm0[mi], qn0[ni], a0[mi][ni], 0, 0, 0);
                a0[mi][ni] = __builtin_amdgcn_mfma_f32_16x16x32_bf16(qm1[mi], qn1[ni], a0[mi][ni], 0, 0, 0);
                a1[mi][ni] = __builtin_amdgcn_mfma_f32_16x16x32_bf16(p0[mi], qn0[ni], a1[mi][ni], 0, 0, 0);
                a2[mi][ni] = __builtin_amdgcn_mfma_f32_16x16x32_bf16(p0[mi], qn1[ni], a2[mi][ni], 0, 0, 0);
                a3[mi][ni] = __builtin_amdgcn_mfma_f32_16x16x32_bf16(p1[mi], qn0[ni], a3[mi][ni], 0, 0, 0);
                a4[mi][ni] = __builtin_amdgcn_mfma_f32_16x16x32_bf16(p1[mi], qn1[ni], a4[mi][ni], 0, 0, 0);
            }
    }
    float* Gp = Gpart + (size_t)(blockIdx.x * 14 + b) * 5 * 4096;
#define STORE_Z(zidx, ACC)                                                     \
    for (int mi = 0; mi < 2; ++mi)                                             \
        for (int r = 0; r < 4; ++r)                                            \
            for (int ni = 0; ni < 2; ++ni)                                     \
                Gp[zidx * 4096 + (mo + mi * 16 + q * 4 + r) * 64 + no + ni * 16 + lm] = ACC[mi][ni][r];
    STORE_Z(0, a0) STORE_Z(1, a1) STORE_Z(2, a2) STORE_Z(3, a3) STORE_Z(4, a4)
#undef STORE_Z
}

// ---------------------------------------------------------------------------
// Gram reduce: G[e] = sum_ks Gpart[ks*286720 + e], e = (b*5+z)*4096 + i
// grid (1120), block 256
// ---------------------------------------------------------------------------
__global__ __launch_bounds__(256) void gram_reduce(
    const float* __restrict__ Gpart, float* __restrict__ G)
{
    const int e = blockIdx.x * 256 + threadIdx.x;
    float s = 0.f;
#pragma unroll
    for (int ks = 0; ks < 32; ++ks) s += Gpart[(size_t)ks * 286720 + e];
    G[e] = s;
}

// ---------------------------------------------------------------------------
// Sandwich: logits from Grams (fp32).  grid (14, 9), block 256
// ---------------------------------------------------------------------------
__global__ __launch_bounds__(256) void sandwich(
    const float* __restrict__ thc_w, const float* __restrict__ phc_w,
    const float* __restrict__ thc_b, const float* __restrict__ phc_b,
    const float* __restrict__ thh_w, const float* __restrict__ phh_w,
    const float* __restrict__ thh_b, const float* __restrict__ phh_b,
    const float* __restrict__ thw_w, const float* __restrict__ phw_w,
    const float* __restrict__ thw_b, const float* __restrict__ phw_b,
    const float* __restrict__ G, const float* __restrict__ S,
    float* __restrict__ f1, float* __restrict__ f2)
{
    __shared__ float Wt[64][65], Wp[64][65], Gl[64][65], Tl[64][65];
    __shared__ float sth[64], sph[64], uu[64], vv[64], btl[64], bpl[64];
    const int b = blockIdx.x, y = blockIdx.y, tid = threadIdx.x;
    const float *Wth_g, *Wph_g, *bth_g, *bph_g, *Gp;
    float* outp; int dl = 0, dp = 0; float Kn;
    if (y == 0) {
        Wth_g = thc_w; Wph_g = phc_w; bth_g = thc_b; bph_g = phc_b;
        Gp = G + (size_t)(b * 5) * 4096; Kn = 16384.f;
        outp = f1 + (size_t)b * 4096;
    } else {
        const int part = (y - 1) / 4, e = (y - 1) & 3;
        dl = e >> 1; dp = e & 1;
        if (part == 0) { Wth_g = thh_w; Wph_g = phh_w; bth_g = thh_b; bph_g = phh_b; }
        else           { Wth_g = thw_w; Wph_g = phw_w; bth_g = thw_b; bph_g = phw_b; }
        Gp = G + (size_t)(b * 5 + 1 + e) * 4096; Kn = 8192.f;
        outp = f2 + (size_t)(part * 14 + b) * 16384;
    }
#pragma unroll
    for (int i = 0; i < 4; ++i) {
        const int id = tid + 256 * i;
        const int r = id >> 4, c4 = (id & 15) * 4;
        float4 v = *(const float4*)&Wth_g[r * 64 + c4];
        Wt[r][c4] = v.x; Wt[r][c4 + 1] = v.y; Wt[r][c4 + 2] = v.z; Wt[r][c4 + 3] = v.w;
        float4 u = *(const float4*)&Wph_g[r * 64 + c4];
        Wp[r][c4] = u.x; Wp[r][c4 + 1] = u.y; Wp[r][c4 + 2] = u.z; Wp[r][c4 + 3] = u.w;
        float4 g = *(const float4*)&Gp[r * 64 + c4];
        Gl[r][c4] = g.x; Gl[r][c4 + 1] = g.y; Gl[r][c4 + 2] = g.z; Gl[r][c4 + 3] = g.w;
    }
    if (tid < 64) {
        if (y == 0) { const float sf = S[b * 128 + tid] + S[b * 128 + 64 + tid]; sth[tid] = sf; sph[tid] = sf; }
        else { sth[tid] = S[dl * 64 + tid]; sph[tid] = S[b * 128 + dp * 64 + tid]; }
        btl[tid] = bth_g[tid]; bpl[tid] = bph_g[tid];
    }
    __syncthreads();
    if (tid < 64) {
        float su = 0.f, sv = 0.f;
        for (int c = 0; c < 64; ++c) { su += Wt[tid][c] * sth[c]; sv += Wp[tid][c] * sph[c]; }
        uu[tid] = su; vv[tid] = sv;
    }
    const int t = tid & 63, qq = tid >> 6;
    float r16[16];
#pragma unroll
    for (int i = 0; i < 16; ++i) r16[i] = 0.f;
    for (int c = 0; c < 64; ++c) {
        const float fv = Wt[t][c];
#pragma unroll
        for (int i = 0; i < 16; ++i) r16[i] += fv * Gl[c][qq * 16 + i];
    }
#pragma unroll
    for (int i = 0; i < 16; ++i) Tl[t][qq * 16 + i] = r16[i];
    __syncthreads();
#pragma unroll
    for (int i = 0; i < 16; ++i) r16[i] = 0.f;
    for (int c = 0; c < 64; ++c) {
        const float tv = Tl[t][c];
#pragma unroll
        for (int i = 0; i < 16; ++i) r16[i] += tv * Wp[qq * 16 + i][c];
    }
    if (y == 0) {
#pragma unroll
        for (int i = 0; i < 16; ++i) {
            const int d = qq * 16 + i;
            outp[t * 64 + d] = r16[i] + uu[t] * bpl[d] + btl[t] * vv[d] + Kn * btl[t] * bpl[d];
        }
    } else {
#pragma unroll
        for (int i = 0; i < 16; ++i) {
            const int tp = qq * 16 + i;
            outp[(2 * t + dl) * 128 + 2 * tp + dp] =
                r16[i] + uu[t] * bpl[tp] + btl[t] * vv[tp] + Kn * btl[t] * bpl[tp];
        }
    }
}

// ---------------------------------------------------------------------------
// Merged softmax + bias dots + de-interleave
// ---------------------------------------------------------------------------
__global__ __launch_bounds__(256) void softmax_all(
    const float* __restrict__ f1, const float* __restrict__ f2,
    const float* __restrict__ gcb, const float* __restrict__ ghb,
    const float* __restrict__ gwb,
    unsigned short* __restrict__ o1, unsigned short* __restrict__ o2d,
    float* __restrict__ B1, float* __restrict__ B2)
{
    __shared__ float red[256];
    __shared__ float mxA[128], invA[128];
    __shared__ float bgl[64];
    const int bx = blockIdx.x, tid = threadIdx.x;
    if (bx < 14) {
        const float* Fb = f1 + (size_t)bx * 4096;
        unsigned short* Ob = o1 + (size_t)bx * 4096;
        if (tid < 64) bgl[tid] = gcb[tid];
        const int d = tid & 63, qq = tid >> 6;
        float mx = -1e30f;
        for (int c = qq * 16; c < qq * 16 + 16; ++c) mx = fmaxf(mx, Fb[c * 64 + d]);
        red[tid] = mx;
        __syncthreads();
        if (tid < 64) mxA[tid] = fmaxf(fmaxf(red[tid], red[64 + tid]), fmaxf(red[128 + tid], red[192 + tid]));
        __syncthreads();
        const float m = mxA[d];
        float s = 0.f;
        for (int c = qq * 16; c < qq * 16 + 16; ++c) s += __expf(Fb[c * 64 + d] - m);
        red[tid] = s;
        __syncthreads();
        if (tid < 64) invA[tid] = 1.f / (red[tid] + red[64 + tid] + red[128 + tid] + red[192 + tid]);
        __syncthreads();
        const int e0 = tid * 16;
        const int d0 = e0 & 63;
        float bp = 0.f;
#pragma unroll
        for (int i = 0; i < 16; i += 4) {
            us4 r4;
            float v0 = __expf(Fb[e0 + i] - mxA[d0 + i]) * invA[d0 + i];
            float v1 = __expf(Fb[e0 + i + 1] - mxA[d0 + i + 1]) * invA[d0 + i + 1];
            float v2 = __expf(Fb[e0 + i + 2] - mxA[d0 + i + 2]) * invA[d0 + i + 2];
            float v3 = __expf(Fb[e0 + i + 3] - mxA[d0 + i + 3]) * invA[d0 + i + 3];
            bp += v0 * bgl[d0 + i] + v1 * bgl[d0 + i + 1] + v2 * bgl[d0 + i + 2] + v3 * bgl[d0 + i + 3];
            r4.x = f2bf(v0); r4.y = f2bf(v1); r4.z = f2bf(v2); r4.w = f2bf(v3);
            *(us4*)&Ob[e0 + i] = r4;
        }
        red[tid] = bp;
        __syncthreads();
        if (tid < 64)
            B1[bx * 64 + tid] = red[tid * 4] + red[tid * 4 + 1] + red[tid * 4 + 2] + red[tid * 4 + 3];
    } else {
        const int idx = bx - 14;
        const float* Fb = f2 + (size_t)idx * 16384;
        if (tid < 64) bgl[tid] = (idx < 14) ? ghb[tid] : gwb[tid];
        const int j = tid & 127, ih = tid >> 7;
        float mx = -1e30f;
        for (int i = ih * 64; i < ih * 64 + 64; ++i) mx = fmaxf(mx, Fb[i * 128 + j]);
        red[tid] = mx;
        __syncthreads();
        if (tid < 128) mxA[tid] = fmaxf(red[tid], red[128 + tid]);
        __syncthreads();
        const float m = mxA[j];
        float s = 0.f;
        for (int i = ih * 64; i < ih * 64 + 64; ++i) s += __expf(Fb[i * 128 + j] - m);
        red[tid] = s;
        __syncthreads();
        if (tid < 128) invA[tid] = 1.f / (red[tid] + red[128 + tid]);
        __syncthreads();
        const int e0 = tid * 64;
        const int irow = tid >> 1;
        const int j0 = e0 & 127;
        unsigned short vt[2][32];
        float bp = 0.f;
        for (int ii = 0; ii < 64; ++ii) {
            const int jj = j0 + ii;
            const float v = __expf(Fb[e0 + ii] - mxA[jj]) * invA[jj];
            bp += v * bgl[jj >> 1];
            vt[jj & 1][ii >> 1] = f2bf(v);
        }
        unsigned short* Od = o2d + (size_t)idx * 16384 + irow * 64 + (j0 >> 1);
#pragma unroll
        for (int dlt = 0; dlt < 2; ++dlt)
#pragma unroll
            for (int ss = 0; ss < 32; ss += 4)
                *(us4*)&Od[dlt * 8192 + ss] = *(us4*)&vt[dlt][ss];
        red[tid] = bp;
        __syncthreads();
        if (tid < 128) B2[idx * 128 + tid] = red[2 * tid] + red[2 * tid + 1];
    }
}

// ---------------------------------------------------------------------------
// kmat via MFMA, LDS-free.  grid (14, 3), block 256
// ---------------------------------------------------------------------------
__global__ __launch_bounds__(256) void kmat(
    const unsigned short* __restrict__ f16_1, const unsigned short* __restrict__ f2d,
    const unsigned short* __restrict__ gT16,
    unsigned short* __restrict__ K1, unsigned short* __restrict__ K2)
{
    const int b = blockIdx.x, y = blockIdx.y, tid = threadIdx.x;
    const int w = tid >> 6, l = tid & 63, lm = l & 15, q = l >> 4;
    if (y == 0) {
        const unsigned short* A = f16_1 + (size_t)b * 4096;
        const unsigned short* Bm = gT16;
        const int mo = (w & 1) * 32, no = (w >> 1) * 32;
        f32x4 acc[2][2] = {};
#pragma unroll
        for (int ks = 0; ks < 2; ++ks) {
            const int k = ks * 32 + q * 8;
            bf16x8 a[2], bb[2];
#pragma unroll
            for (int mi = 0; mi < 2; ++mi) a[mi] = *(const bf16x8*)&A[(mo + mi * 16 + lm) * 64 + k];
#pragma unroll
            for (int ni = 0; ni < 2; ++ni) bb[ni] = *(const bf16x8*)&Bm[(no + ni * 16 + lm) * 64 + k];
#pragma unroll
            for (int mi = 0; mi < 2; ++mi)
#pragma unroll
                for (int ni = 0; ni < 2; ++ni)
                    acc[mi][ni] = __builtin_amdgcn_mfma_f32_16x16x32_bf16(a[mi], bb[ni], acc[mi][ni], 0, 0, 0);
        }
        unsigned short* Kp = K1 + (size_t)b * 4096;
#pragma unroll
        for (int mi = 0; mi < 2; ++mi)
#pragma unroll
            for (int r = 0; r < 4; ++r)
#pragma unroll
                for (int ni = 0; ni < 2; ++ni)
                    Kp[(mo + mi * 16 + q * 4 + r) * 64 + no + ni * 16 + lm] = f2bf(acc[mi][ni][r]);
    } else {
        const int part = y - 1;
        const unsigned short* Bm = gT16 + (size_t)(1 + part) * 4096;
        unsigned short* Kp = K2 + (size_t)(part * 14 + b) * 16384;
        for (int dlt = 0; dlt < 2; ++dlt) {
            const unsigned short* A = f2d + (size_t)(part * 14 + b) * 16384 + dlt * 8192;
            const int mo = (w & 1) * 64, no = (w >> 1) * 32;
            f32x4 acc[4][2] = {};
#pragma unroll
            for (int ks = 0; ks < 2; ++ks) {
                const int k = ks * 32 + q * 8;
                bf16x8 a[4], bb[2];
#pragma unroll
                for (int mi = 0; mi < 4; ++mi) a[mi] = *(const bf16x8*)&A[(mo + mi * 16 + lm) * 64 + k];
#pragma unroll
                for (int ni = 0; ni < 2; ++ni) bb[ni] = *(const bf16x8*)&Bm[(no + ni * 16 + lm) * 64 + k];
#pragma unroll
                for (int mi = 0; mi < 4; ++mi)
#pragma unroll
                    for (int ni = 0; ni < 2; ++ni)
                        acc[mi][ni] = __builtin_amdgcn_mfma_f32_16x16x32_bf16(a[mi], bb[ni], acc[mi][ni], 0, 0, 0);
            }
#pragma unroll
            for (int mi = 0; mi < 4; ++mi)
#pragma unroll
                for (int r = 0; r < 4; ++r)
#pragma unroll
                    for (int ni = 0; ni < 2; ++ni)
                        Kp[dlt * 8192 + (mo + mi * 16 + q * 4 + r) * 64 + no + ni * 16 + lm] = f2bf(acc[mi][ni][r]);
        }
    }
}

// ---------------------------------------------------------------------------
// Residual fold, LDS-free.  grid (256), block 256.
// ---------------------------------------------------------------------------
__global__ __launch_bounds__(256) void fold_res(
    const unsigned short* __restrict__ Wcomb, const unsigned short* __restrict__ XT,
    float* __restrict__ Out)
{
    const int tid = threadIdx.x;
    const int w = tid >> 6, l = tid & 63, lm = l & 15, q = l >> 4;
    const int p0 = blockIdx.x * 64 + (w >> 1) * 32;
    const int oh = (w & 1) * 32;
    f32x4 acc[2][2] = {};
    for (int b = 0; b < 14; ++b) {
#pragma unroll
        for (int ks = 0; ks < 2; ++ks) {
            const int c0 = ks * 32 + q * 8;
            bf16x8 a[2], bb[2];
#pragma unroll
            for (int mi = 0; mi < 2; ++mi)
                a[mi] = *(const bf16x8*)&Wcomb[(oh + mi * 16 + lm) * 896 + b * 64 + c0];
#pragma unroll
            for (int ni = 0; ni < 2; ++ni)
                bb[ni] = *(const bf16x8*)&XT[(size_t)b * CN + (size_t)(p0 + ni * 16 + lm) * 64 + c0];
#pragma unroll
            for (int mi = 0; mi < 2; ++mi)
#pragma unroll
                for (int ni = 0; ni < 2; ++ni)
                    acc[mi][ni] = __builtin_amdgcn_mfma_f32_16x16x32_bf16(a[mi], bb[ni], acc[mi][ni], 0, 0, 0);
        }
    }
#pragma unroll
    for (int mi = 0; mi < 2; ++mi)
#pragma unroll
        for (int r = 0; r < 4; ++r) {
            const int o = oh + mi * 16 + q * 4 + r;
#pragma unroll
            for (int ni = 0; ni < 2; ++ni)
                Out[(size_t)o * NPIX + p0 + ni * 16 + lm] = acc[mi][ni][r];
        }
}

// ---------------------------------------------------------------------------
// pv1: Y[p*64+c] = sum_{c'} xT[p][c'] K1[c][c'] + B1[c].  grid (64,1,14)
// ---------------------------------------------------------------------------
__global__ __launch_bounds__(256) void pv1k(
    const unsigned short* __restrict__ XT, const unsigned short* __restrict__ K1,
    const float* __restrict__ B1, unsigned short* __restrict__ Y)
{
    const int tid = threadIdx.x;
    const int w = tid >> 6, l = tid & 63, lm = l & 15, q = l >> 4;
    const int b = blockIdx.z;
    const int p0 = blockIdx.x * 256 + w * 64;
    const unsigned short* Xb = XT + (size_t)b * CN;
    const unsigned short* Kb = K1 + (size_t)b * 4096;
    f32x4 acc[4][4] = {};
#pragma unroll
    for (int ks = 0; ks < 2; ++ks) {
        const int c0 = ks * 32 + q * 8;
        bf16x8 a[4], bb[4];
#pragma unroll
        for (int mi = 0; mi < 4; ++mi) a[mi] = *(const bf16x8*)&Xb[(size_t)(p0 + mi * 16 + lm) * 64 + c0];
#pragma unroll
        for (int ni = 0; ni < 4; ++ni) bb[ni] = *(const bf16x8*)&Kb[(ni * 16 + lm) * 64 + c0];
#pragma unroll
        for (int mi = 0; mi < 4; ++mi)
#pragma unroll
            for (int ni = 0; ni < 4; ++ni)
                acc[mi][ni] = __builtin_amdgcn_mfma_f32_16x16x32_bf16(a[mi], bb[ni], acc[mi][ni], 0, 0, 0);
    }
    unsigned short* Yb = Y + (size_t)b * CN;
#pragma unroll
    for (int mi = 0; mi < 4; ++mi)
#pragma unroll
        for (int r = 0; r < 4; ++r) {
            const int p = p0 + mi * 16 + q * 4 + r;
#pragma unroll
            for (int ni = 0; ni < 4; ++ni) {
                const int c = ni * 16 + lm;
                Yb[(size_t)p * 64 + c] = f2bf(acc[mi][ni][r] + B1[b * 64 + c]);
            }
        }
}

// ---------------------------------------------------------------------------
// pv2/3: Y[k*128+i] = sum_dlt sum_c xT[dlt*8192+k][c] K2[dlt][i][c] + B2[i]
// grid (32, 2, 28)
// ---------------------------------------------------------------------------
__global__ __launch_bounds__(256) void pv23k(
    const unsigned short* __restrict__ XT, const unsigned short* __restrict__ K2,
    const float* __restrict__ B2, unsigned short* __restrict__ Y2,
    unsigned short* __restrict__ Y3)
{
    const int tid = threadIdx.x;
    const int w = tid >> 6, l = tid & 63, lm = l & 15, q = l >> 4;
    const int part = blockIdx.z / 14, b = blockIdx.z % 14;
    const int k00 = blockIdx.x * 256 + w * 64;
    const int i0 = blockIdx.y * 64;
    const unsigned short* Xb = XT + (size_t)b * CN;
    const unsigned short* Kb = K2 + (size_t)(part * 14 + b) * 16384;
    const float* Bb = B2 + (part * 14 + b) * 128;
    f32x4 acc[4][4] = {};
#pragma unroll
    for (int dlt = 0; dlt < 2; ++dlt) {
#pragma unroll
        for (int ks = 0; ks < 2; ++ks) {
            const int c0 = ks * 32 + q * 8;
            bf16x8 a[4], bb[4];
#pragma unroll
            for (int mi = 0; mi < 4; ++mi)
                a[mi] = *(const bf16x8*)&Xb[(size_t)(dlt * 8192 + k00 + mi * 16 + lm) * 64 + c0];
#pragma unroll
            for (int ni = 0; ni < 4; ++ni)
                bb[ni] = *(const bf16x8*)&Kb[dlt * 8192 + (i0 + ni * 16 + lm) * 64 + c0];
#pragma unroll
            for (int mi = 0; mi < 4; ++mi)
#pragma unroll
                for (int ni = 0; ni < 4; ++ni)
                    acc[mi][ni] = __builtin_amdgcn_mfma_f32_16x16x32_bf16(a[mi], bb[ni], acc[mi][ni], 0, 0, 0);
        }
    }
    unsigned short* Yb = (part ? Y3 : Y2) + (size_t)b * CN;
#pragma unroll
    for (int mi = 0; mi < 4; ++mi)
#pragma unroll
        for (int r = 0; r < 4; ++r) {
            const int k = k00 + mi * 16 + q * 4 + r;
#pragma unroll
            for (int ni = 0; ni < 4; ++ni) {
                const int ii = i0 + ni * 16 + lm;
                Yb[(size_t)k * 128 + ii] = f2bf(acc[mi][ni][r] + Bb[ii]);
            }
        }
}

// ---------------------------------------------------------------------------
// Merged y-fold: Out[o][pix] += sum_t M[z][t][o][c2] y_z[t][c2][pix]
// grid (128, 2, 3), block 256
// ---------------------------------------------------------------------------
__global__ __launch_bounds__(256) void yfold(
    const unsigned short* __restrict__ M16,
    const unsigned short* __restrict__ Y1, const unsigned short* __restrict__ Y2,
    const unsigned short* __restrict__ Y3, float* __restrict__ Out)
{
    __shared__ unsigned short As[64][LP];
    __shared__ unsigned short Ss[128][LP];
    const int tid = threadIdx.x;
    const int z = blockIdx.z;
    const unsigned short* Ap = M16 + (size_t)z * 14 * 4096;
    const unsigned short* S = (z == 0) ? Y1 : (z == 1) ? Y2 : Y3;
    const int p0 = blockIdx.x * 128;
    const int t0 = blockIdx.y * 7;
    const int w = tid >> 6, l = tid & 63, lm = l & 15, q = l >> 4;
    const int mo = (w & 1) * 32;
    const int no = (w >> 1) * 64;
    f32x4 acc[2][4] = {};

    for (int t = t0; t < t0 + 7; ++t) {
        __syncthreads();
#pragma unroll
        for (int i = 0; i < 2; ++i) {
            const int ch = tid + 256 * i;
            const int row = ch >> 3, c8 = (ch & 7) * 8;
            *(bf16x8*)&As[row][c8] = *(const bf16x8*)&Ap[(size_t)t * 4096 + (size_t)row * 64 + c8];
        }
#pragma unroll
        for (int i = 0; i < 4; ++i) {
            const int id = tid + 256 * i;
            const int c = id & 63, p8 = (id >> 6) * 8;
            bf16x8 v = *(const bf16x8*)&S[(size_t)t * CN + (size_t)c * NPIX + p0 + p8];
#pragma unroll
            for (int j = 0; j < 8; ++j) Ss[p8 + j][c] = (unsigned short)v[j];
        }
        __syncthreads();
#pragma unroll
        for (int ks = 0; ks < 2; ++ks) {
            const int c0 = ks * 32 + q * 8;
            bf16x8 a[2], bb[4];
#pragma unroll
            for (int mi = 0; mi < 2; ++mi) a[mi] = *(const bf16x8*)&As[mo + mi * 16 + lm][c0];
#pragma unroll
            for (int ni = 0; ni < 4; ++ni) bb[ni] = *(const bf16x8*)&Ss[no + ni * 16 + lm][c0];
#pragma unroll
            for (int mi = 0; mi < 2; ++mi)
#pragma unroll
                for (int ni = 0; ni < 4; ++ni)
                    acc[mi][ni] = __builtin_amdgcn_mfma_f32_16x16x32_bf16(a[mi], bb[ni], acc[mi][ni], 0, 0, 0);
        }
    }
#pragma unroll
    for (int mi = 0; mi < 2; ++mi)
#pragma unroll
        for (int r = 0; r < 4; ++r) {
            const int o = mo + mi * 16 + q * 4 + r;
#pragma unroll
            for (int ni = 0; ni < 4; ++ni)
                atomicAdd(&Out[(size_t)o * NPIX + p0 + no + ni * 16 + lm], acc[mi][ni][r]);
        }
}

// out = leaky(out + cb[o])
__global__ __launch_bounds__(256) void leaky_cb(float* __restrict__ O, const float* __restrict__ cb)
{
    const int i = blockIdx.x * 256 + threadIdx.x;
    float4 v = ((float4*)O)[i];
    const float b = cb[(i * 4) >> 14];
    v.x += b; v.y += b; v.z += b; v.w += b;
    v.x = v.x >= 0.f ? v.x : 0.2f * v.x;
    v.y = v.y >= 0.f ? v.y : 0.2f * v.y;
    v.z = v.z >= 0.f ? v.z : 0.2f * v.z;
    v.w = v.w >= 0.f ? v.w : 0.2f * v.w;
    ((float4*)O)[i] = v;
}

extern "C" void kernel_launch(void* const* d_in, const int* in_sizes, int n_in,
                              void* d_out, int out_size, void* d_ws, size_t ws_size,
                              hipStream_t stream)
{
    const float* x     = (const float*)d_in[0];
    const float* gc_w  = (const float*)d_in[1];
    const float* gc_b  = (const float*)d_in[2];
    const float* thc_w = (const float*)d_in[3];
    const float* thc_b = (const float*)d_in[4];
    const float* phc_w = (const float*)d_in[5];
    const float* phc_b = (const float*)d_in[6];
    const float* Wc_w  = (const float*)d_in[7];
    const float* Wc_b  = (const float*)d_in[8];
    const float* gh_w  = (const float*)d_in[9];
    const float* gh_b  = (const float*)d_in[10];
    const float* thh_w = (const float*)d_in[11];
    const float* thh_b = (const float*)d_in[12];
    const float* phh_w = (const float*)d_in[13];
    const float* phh_b = (const float*)d_in[14];
    const float* Wh_w  = (const float*)d_in[15];
    const float* Wh_b  = (const float*)d_in[16];
    const float* gw_w  = (const float*)d_in[17];
    const float* gw_b  = (const float*)d_in[18];
    const float* thw_w = (const float*)d_in[19];
    const float* thw_b = (const float*)d_in[20];
    const float* phw_w = (const float*)d_in[21];
    const float* phw_b = (const float*)d_in[22];
    const float* Ww_w  = (const float*)d_in[23];
    const float* Ww_b  = (const float*)d_in[24];
    const float* fus_w = (const float*)d_in[25];
    const float* fus_b = (const float*)d_in[26];

    float* out = (float*)d_out;

    char* p = (char*)d_ws;
    unsigned short* xb   = (unsigned short*)p; p += (size_t)BURST * CN * 2;
    unsigned short* xT   = (unsigned short*)p; p += (size_t)BURST * CN * 2;
    unsigned short* y1   = (unsigned short*)p; p += (size_t)BURST * CN * 2;
    unsigned short* y2   = (unsigned short*)p; p += (size_t)BURST * CN * 2;
    unsigned short* y3   = (unsigned short*)p; p += (size_t)BURST * CN * 2;
    float*          Gbuf = (float*)p;          p += (size_t)BURST * 5 * 4096 * 4;
    float*          sbuf = (float*)p;          p += (size_t)BURST * 2 * 64 * 4;
    float*          f1b  = (float*)p;          p += (size_t)BURST * 4096 * 4;
    float*          f2b  = (float*)p;          p += (size_t)2 * BURST * 16384 * 4;
    unsigned short* f16_1 = (unsigned short*)p; p += (size_t)BURST * 4096 * 2;
    unsigned short* f2d  = (unsigned short*)p; p += (size_t)2 * BURST * 16384 * 2;
    unsigned short* K1   = (unsigned short*)p; p += (size_t)BURST * 4096 * 2;
    unsigned short* K2   = (unsigned short*)p; p += (size_t)2 * BURST * 16384 * 2;
    float*          B1   = (float*)p;          p += (size_t)BURST * 64 * 4;
    float*          B2   = (float*)p;          p += (size_t)2 * BURST * 128 * 4;
    unsigned short* M16  = (unsigned short*)p; p += (size_t)42 * 4096 * 2;
    unsigned short* Wc16 = (unsigned short*)p; p += (size_t)64 * 896 * 2;
    unsigned short* gT16 = (unsigned short*)p; p += (size_t)3 * 4096 * 2;
    float*          cbv  = (float*)p;          p += 256;

    // Gram partials alias y1/y2 (dead before pv1k/pv23k write them):
    float* Gpart = (float*)y1;   // 32*286720*4 = 36.7 MB < y1+y2 (58.7 MB)

    hipMemsetAsync(sbuf, 0, (size_t)BURST * 2 * 64 * 4, stream);

    cast_x<<<dim3(128, 14), 256, 0, stream>>>(x, xb, xT, sbuf);
    precompute<<<109, 256, 0, stream>>>(fus_w, fus_b, Wc_w, Wc_b, Wh_w, Wh_b, Ww_w, Ww_b,
                                        gc_w, gh_w, gw_w, M16, Wc16, cbv, gT16);
    gram<<<dim3(32, 14), 256, 0, stream>>>(xb, Gpart);
    gram_reduce<<<1120, 256, 0, stream>>>(Gpart, Gbuf);
    sandwich<<<dim3(14, 9), 256, 0, stream>>>(
        thc_w, phc_w, thc_b, phc_b, thh_w, phh_w, thh_b, phh_b,
        thw_w, phw_w, thw_b, phw_b, Gbuf, sbuf, f1b, f2b);
    softmax_all<<<42, 256, 0, stream>>>(f1b, f2b, gc_b, gh_b, gw_b,
                                        f16_1, f2d, B1, B2);
    kmat<<<dim3(14, 3), 256, 0, stream>>>(f16_1, f2d, gT16, K1, K2);
    fold_res<<<256, 256, 0, stream>>>(Wc16, xT, out);
    pv1k<<<dim3(64, 1, BURST), 256, 0, stream>>>(xT, K1, B1, y1);
    pv23k<<<dim3(32, 2, 2 * BURST), 256, 0, stream>>>(xT, K2, B2, y2, y3);
    yfold<<<dim3(128, 2, 3), 256, 0, stream>>>(M16, y1, y2, y3, out);
    leaky_cb<<<1024, 256, 0, stream>>>(out, cbv);
}